// Round 1
// baseline (12244.844 us; speedup 1.0000x reference)
//
#include <hip/hip_runtime.h>
#include <hip/hip_bf16.h>

#define BB 4
#define TT 2048
#define HID 1024
#define NH 4
#define KD 512
#define VD 1024
#define DK 128
#define DV 256
#define RR 32
#define R5 160
#define GLR 64
#define BT (BB*TT)

// ---------------- elementwise: xz = x + (shift(x) - x) * mu0 ----------------
__global__ __launch_bounds__(256) void lerp0_kernel(const float* __restrict__ x,
    const float* __restrict__ mu0, float* __restrict__ out) {
  size_t i = (size_t)blockIdx.x * 256 + threadIdx.x;     // float4 index
  const int ncol4 = HID / 4;
  int c4 = (int)(i % ncol4);
  size_t tok = i / ncol4;
  int t = (int)(tok & (TT - 1));
  float4 xv = ((const float4*)x)[i];
  float4 m  = ((const float4*)mu0)[c4];
  float4 xs = make_float4(0.f, 0.f, 0.f, 0.f);
  if (t) xs = ((const float4*)x)[i - ncol4];
  float4 r;
  r.x = xv.x + (xs.x - xv.x) * m.x;
  r.y = xv.y + (xs.y - xv.y) * m.y;
  r.z = xv.z + (xs.z - xv.z) * m.z;
  r.w = xv.w + (xs.w - xv.w) * m.w;
  ((float4*)out)[i] = r;
}

// ---------------- generic fp32 GEMM: C = epi(X @ W^T) ----------------
// X: (M,K) row stride lda; W: (N,K) row stride ldb; C: (M,N) row stride ldc.
// EPI: 0 none | 1 tanh | 2 exp(-exp(v + bias[n])) | 3 lerp: x + (shift-x)*(v+bias[n])
template<int EPI>
__global__ __launch_bounds__(256) void gemm_bt(
    const float* __restrict__ X, int lda,
    const float* __restrict__ W, int ldb,
    float* __restrict__ C, int ldc,
    int M, int N, int K,
    const float* __restrict__ bias,
    const float* __restrict__ ex) {
  __shared__ float As[16][132];
  __shared__ float Bs[16][132];
  const int tid = threadIdx.x;
  const int tx = tid & 15;
  const int ty = tid >> 4;
  const int m0 = blockIdx.y * 128;
  const int n0 = blockIdx.x * 128;
  float acc[8][8];
#pragma unroll
  for (int i = 0; i < 8; ++i)
#pragma unroll
    for (int j = 0; j < 8; ++j) acc[i][j] = 0.f;

  for (int k0 = 0; k0 < K; k0 += 16) {
#pragma unroll
    for (int s = 0; s < 2; ++s) {
      int q = s * 256 + tid;
      int row = q >> 2;
      int c4 = q & 3;
      float4 a = *(const float4*)&X[(size_t)(m0 + row) * lda + k0 + c4 * 4];
      As[c4 * 4 + 0][row] = a.x; As[c4 * 4 + 1][row] = a.y;
      As[c4 * 4 + 2][row] = a.z; As[c4 * 4 + 3][row] = a.w;
      int wr = n0 + row;
      float4 b = make_float4(0.f, 0.f, 0.f, 0.f);
      if (wr < N) b = *(const float4*)&W[(size_t)wr * ldb + k0 + c4 * 4];
      Bs[c4 * 4 + 0][row] = b.x; Bs[c4 * 4 + 1][row] = b.y;
      Bs[c4 * 4 + 2][row] = b.z; Bs[c4 * 4 + 3][row] = b.w;
    }
    __syncthreads();
#pragma unroll
    for (int kk = 0; kk < 16; ++kk) {
      float a[8], b[8];
#pragma unroll
      for (int p = 0; p < 4; ++p) {
        float2 t2 = *(const float2*)&As[kk][ty * 8 + p * 2];
        a[p * 2] = t2.x; a[p * 2 + 1] = t2.y;
        float2 u2 = *(const float2*)&Bs[kk][tx * 8 + p * 2];
        b[p * 2] = u2.x; b[p * 2 + 1] = u2.y;
      }
#pragma unroll
      for (int i = 0; i < 8; ++i)
#pragma unroll
        for (int j = 0; j < 8; ++j)
          acc[i][j] = fmaf(a[i], b[j], acc[i][j]);
    }
    __syncthreads();
  }
#pragma unroll
  for (int i = 0; i < 8; ++i) {
    int m = m0 + ty * 8 + i;
#pragma unroll
    for (int j = 0; j < 8; ++j) {
      int n = n0 + tx * 8 + j;
      if (n < N) {
        float v = acc[i][j];
        float res;
        if (EPI == 0) {
          res = v;
        } else if (EPI == 1) {
          res = tanhf(v);
        } else if (EPI == 2) {
          res = expf(-expf(v + bias[n]));
        } else {
          float xv = ex[(size_t)m * HID + n];
          int t = m & (TT - 1);
          float xs = t ? ex[(size_t)(m - 1) * HID + n] : 0.f;
          res = xv + (xs - xv) * (v + bias[n]);
        }
        C[(size_t)m * ldc + n] = res;
      }
    }
  }
}

// ---------------- c[b,h,t] = sum_dk r*u*k ----------------
__global__ __launch_bounds__(256) void calc_c(const float* __restrict__ r,
    const float* __restrict__ k, const float* __restrict__ u,
    float* __restrict__ c) {
  int idx = blockIdx.x * 4 + (threadIdx.x >> 6);   // (b*NH+h)*TT + t
  int lane = threadIdx.x & 63;
  int t = idx & (TT - 1);
  int bh = idx >> 11;
  int h = bh & (NH - 1);
  int b = bh >> 2;
  const float* rp = r + (size_t)(b * TT + t) * KD + h * DK;
  const float* kp = k + (size_t)(b * TT + t) * KD + h * DK;
  const float* up = u + h * DK;
  float2 rv = *(const float2*)&rp[lane * 2];
  float2 kv = *(const float2*)&kp[lane * 2];
  float2 uv = *(const float2*)&up[lane * 2];
  float p = rv.x * uv.x * kv.x + rv.y * uv.y * kv.y;
#pragma unroll
  for (int off = 32; off > 0; off >>= 1) p += __shfl_xor(p, off);
  if (lane == 0) c[idx] = p;
}

// ---------------- sequential scan: one block per (b,h), thread owns dv ----------------
__global__ __launch_bounds__(256) void scan_kernel(
    const float* __restrict__ r, const float* __restrict__ k,
    const float* __restrict__ d, const float* __restrict__ v,
    const float* __restrict__ c, float* __restrict__ o) {
  const int bh = blockIdx.x;
  const int b = bh >> 2, h = bh & (NH - 1);
  const int dv = threadIdx.x;
  float S[DK];
#pragma unroll
  for (int i = 0; i < DK; ++i) S[i] = 0.f;
  const float* rp = r + (size_t)b * TT * KD + h * DK;
  const float* kp = k + (size_t)b * TT * KD + h * DK;
  const float* dp = d + (size_t)b * TT * KD + h * DK;
  const float* vp = v + (size_t)b * TT * VD + h * DV + dv;
  const float* cp = c + (size_t)bh * TT;
  float* op = o + (size_t)b * TT * VD + h * DV + dv;
  for (int t = 0; t < TT; ++t) {
    float vt = *vp;
    float oa0 = 0.f, oa1 = 0.f, oa2 = 0.f, oa3 = 0.f;
#pragma unroll
    for (int q = 0; q < DK / 4; ++q) {
      float4 rq = *(const float4*)&rp[q * 4];
      float4 kq = *(const float4*)&kp[q * 4];
      float4 dq = *(const float4*)&dp[q * 4];
      oa0 = fmaf(rq.x, S[q * 4 + 0], oa0);
      oa1 = fmaf(rq.y, S[q * 4 + 1], oa1);
      oa2 = fmaf(rq.z, S[q * 4 + 2], oa2);
      oa3 = fmaf(rq.w, S[q * 4 + 3], oa3);
      S[q * 4 + 0] = fmaf(dq.x, S[q * 4 + 0], kq.x * vt);
      S[q * 4 + 1] = fmaf(dq.y, S[q * 4 + 1], kq.y * vt);
      S[q * 4 + 2] = fmaf(dq.z, S[q * 4 + 2], kq.z * vt);
      S[q * 4 + 3] = fmaf(dq.w, S[q * 4 + 3], kq.w * vt);
    }
    float oacc = (oa0 + oa1) + (oa2 + oa3) + cp[t] * vt;
    *op = oacc;
    rp += KD; kp += KD; dp += KD; vp += VD; op += VD;
  }
}

// ---------------- GroupNorm (per b,t,h over DV) + gn affine + silu(g) gate ----------------
__global__ __launch_bounds__(256) void gn_gate(const float* __restrict__ o,
    const float* __restrict__ g, const float* __restrict__ gnw,
    const float* __restrict__ gnb, float* __restrict__ out) {
  int tok = blockIdx.x;
  int tid = threadIdx.x;
  __shared__ float s1[4], s2[4];
  for (int h = 0; h < NH; ++h) {
    int col = h * DV + tid;
    float val = o[(size_t)tok * VD + col];
    float a = val, bsq = val * val;
#pragma unroll
    for (int off = 32; off > 0; off >>= 1) {
      a += __shfl_xor(a, off);
      bsq += __shfl_xor(bsq, off);
    }
    int wid = tid >> 6;
    if ((tid & 63) == 0) { s1[wid] = a; s2[wid] = bsq; }
    __syncthreads();
    float S1 = s1[0] + s1[1] + s1[2] + s1[3];
    float S2 = s2[0] + s2[1] + s2[2] + s2[3];
    float mean = S1 * (1.f / DV);
    float var = S2 * (1.f / DV) - mean * mean;
    float xn = (val - mean) * rsqrtf(var + 1e-5f);
    float gv = g[(size_t)tok * VD + col];
    float sig = gv / (1.f + expf(-gv));          // silu(g) = g*sigmoid(g)
    out[(size_t)tok * VD + col] = (xn * gnw[col] + gnb[col]) * sig;
    __syncthreads();
  }
}

extern "C" void kernel_launch(void* const* d_in, const int* in_sizes, int n_in,
                              void* d_out, int out_size, void* d_ws, size_t ws_size,
                              hipStream_t stream) {
  const float* x      = (const float*)d_in[0];
  const float* mu0    = (const float*)d_in[1];
  const float* W_x0   = (const float*)d_in[2];
  const float* W_x2   = (const float*)d_in[3];
  const float* x_bias = (const float*)d_in[4];
  const float* W_r    = (const float*)d_in[5];
  const float* W_w1   = (const float*)d_in[6];
  const float* W_w2   = (const float*)d_in[7];
  const float* b_w2   = (const float*)d_in[8];
  const float* W_k    = (const float*)d_in[9];
  const float* W_v    = (const float*)d_in[10];
  const float* W_g    = (const float*)d_in[11];
  const float* bonus  = (const float*)d_in[12];
  const float* gnw    = (const float*)d_in[13];
  const float* gnb    = (const float*)d_in[14];
  const float* W_o    = (const float*)d_in[15];
  float* out = (float*)d_out;

  float* ws = (float*)d_ws;
  size_t off = 0;
  float* buf  = ws + off; off += (size_t)BT * HID;   // reused: xz, lerped inputs, gated out
  float* xp   = ws + off; off += (size_t)BT * R5;
  float* rb   = ws + off; off += (size_t)BT * KD;
  float* db   = ws + off; off += (size_t)BT * KD;
  float* kb   = ws + off; off += (size_t)BT * KD;
  float* vb   = ws + off; off += (size_t)BT * VD;
  float* gb   = ws + off; off += (size_t)BT * VD;
  float* wlow = ws + off; off += (size_t)BT * GLR;
  float* cb   = ws + off; off += (size_t)BB * NH * TT;
  float* ob   = ws + off; off += (size_t)BT * VD;

  dim3 blk(256);

  // xz = lerp(x, mu0); xp = tanh(xz @ W_x0^T)
  lerp0_kernel<<<dim3(BT * HID / 1024), blk, 0, stream>>>(x, mu0, buf);
  gemm_bt<1><<<dim3(2, 64), blk, 0, stream>>>(buf, HID, W_x0, HID, xp, R5,
                                              BT, R5, HID, nullptr, nullptr);
  // slot 0 -> r
  gemm_bt<3><<<dim3(8, 64), blk, 0, stream>>>(xp + 0 * RR, R5, W_x2 + 0 * RR, R5, buf, HID,
                                              BT, HID, RR, x_bias + 0 * HID, x);
  gemm_bt<0><<<dim3(4, 64), blk, 0, stream>>>(buf, HID, W_r, HID, rb, KD,
                                              BT, KD, HID, nullptr, nullptr);
  // slot 1 -> w (lora down+tanh, up+bias, then decay = exp(-exp(w)))
  gemm_bt<3><<<dim3(8, 64), blk, 0, stream>>>(xp + 1 * RR, R5, W_x2 + 1 * RR, R5, buf, HID,
                                              BT, HID, RR, x_bias + 1 * HID, x);
  gemm_bt<1><<<dim3(1, 64), blk, 0, stream>>>(buf, HID, W_w1, HID, wlow, GLR,
                                              BT, GLR, HID, nullptr, nullptr);
  gemm_bt<2><<<dim3(4, 64), blk, 0, stream>>>(wlow, GLR, W_w2, GLR, db, KD,
                                              BT, KD, GLR, b_w2, nullptr);
  // slot 2 -> k
  gemm_bt<3><<<dim3(8, 64), blk, 0, stream>>>(xp + 2 * RR, R5, W_x2 + 2 * RR, R5, buf, HID,
                                              BT, HID, RR, x_bias + 2 * HID, x);
  gemm_bt<0><<<dim3(4, 64), blk, 0, stream>>>(buf, HID, W_k, HID, kb, KD,
                                              BT, KD, HID, nullptr, nullptr);
  // slot 3 -> v
  gemm_bt<3><<<dim3(8, 64), blk, 0, stream>>>(xp + 3 * RR, R5, W_x2 + 3 * RR, R5, buf, HID,
                                              BT, HID, RR, x_bias + 3 * HID, x);
  gemm_bt<0><<<dim3(8, 64), blk, 0, stream>>>(buf, HID, W_v, HID, vb, VD,
                                              BT, VD, HID, nullptr, nullptr);
  // slot 4 -> g
  gemm_bt<3><<<dim3(8, 64), blk, 0, stream>>>(xp + 4 * RR, R5, W_x2 + 4 * RR, R5, buf, HID,
                                              BT, HID, RR, x_bias + 4 * HID, x);
  gemm_bt<0><<<dim3(8, 64), blk, 0, stream>>>(buf, HID, W_g, HID, gb, VD,
                                              BT, VD, HID, nullptr, nullptr);

  // bonus scalar, scan, groupnorm+gate, final projection
  calc_c<<<dim3(BB * NH * TT / 4), blk, 0, stream>>>(rb, kb, bonus, cb);
  scan_kernel<<<dim3(BB * NH), blk, 0, stream>>>(rb, kb, db, vb, cb, ob);
  gn_gate<<<dim3(BT), blk, 0, stream>>>(ob, gb, gnw, gnb, buf);
  gemm_bt<0><<<dim3(8, 64), blk, 0, stream>>>(buf, HID, W_o, HID, out, HID,
                                              BT, HID, HID, nullptr, nullptr);
}

// Round 3
// 3019.481 us; speedup vs baseline: 4.0553x; 4.0553x over previous
//
#include <hip/hip_runtime.h>
#include <hip/hip_bf16.h>

#define BB 4
#define TT 2048
#define HID 1024
#define NH 4
#define KD 512
#define VD 1024
#define DK 128
#define DV 256
#define RR 32
#define R5 160
#define GLR 64
#define BT (BB*TT)

// ---------------- elementwise: xz = x + (shift(x) - x) * mu0 ----------------
__global__ __launch_bounds__(256) void lerp0_kernel(const float* __restrict__ x,
    const float* __restrict__ mu0, float* __restrict__ out) {
  size_t i = (size_t)blockIdx.x * 256 + threadIdx.x;     // float4 index
  const int ncol4 = HID / 4;
  int c4 = (int)(i % ncol4);
  size_t tok = i / ncol4;
  int t = (int)(tok & (TT - 1));
  float4 xv = ((const float4*)x)[i];
  float4 m  = ((const float4*)mu0)[c4];
  float4 xs = make_float4(0.f, 0.f, 0.f, 0.f);
  if (t) xs = ((const float4*)x)[i - ncol4];
  float4 r;
  r.x = xv.x + (xs.x - xv.x) * m.x;
  r.y = xv.y + (xs.y - xv.y) * m.y;
  r.z = xv.z + (xs.z - xv.z) * m.z;
  r.w = xv.w + (xs.w - xv.w) * m.w;
  ((float4*)out)[i] = r;
}

// ---------------- generic fp32 GEMM: C = epi(X @ W^T) ----------------
// X: (M,K) row stride lda; W: (N,K) row stride ldb; C: (M,N) row stride ldc.
// EPI: 0 none | 1 tanh | 2 exp(-exp(v + bias[n])) | 3 lerp: x + (shift-x)*(v+bias[n])
template<int EPI>
__global__ __launch_bounds__(256) void gemm_bt(
    const float* __restrict__ X, int lda,
    const float* __restrict__ W, int ldb,
    float* __restrict__ C, int ldc,
    int M, int N, int K,
    const float* __restrict__ bias,
    const float* __restrict__ ex) {
  __shared__ float As[16][132];
  __shared__ float Bs[16][132];
  const int tid = threadIdx.x;
  const int tx = tid & 15;
  const int ty = tid >> 4;
  const int m0 = blockIdx.y * 128;
  const int n0 = blockIdx.x * 128;
  float acc[8][8];
#pragma unroll
  for (int i = 0; i < 8; ++i)
#pragma unroll
    for (int j = 0; j < 8; ++j) acc[i][j] = 0.f;

  for (int k0 = 0; k0 < K; k0 += 16) {
#pragma unroll
    for (int s = 0; s < 2; ++s) {
      int q = s * 256 + tid;
      int row = q >> 2;
      int c4 = q & 3;
      float4 a = *(const float4*)&X[(size_t)(m0 + row) * lda + k0 + c4 * 4];
      As[c4 * 4 + 0][row] = a.x; As[c4 * 4 + 1][row] = a.y;
      As[c4 * 4 + 2][row] = a.z; As[c4 * 4 + 3][row] = a.w;
      int wr = n0 + row;
      float4 b = make_float4(0.f, 0.f, 0.f, 0.f);
      if (wr < N) b = *(const float4*)&W[(size_t)wr * ldb + k0 + c4 * 4];
      Bs[c4 * 4 + 0][row] = b.x; Bs[c4 * 4 + 1][row] = b.y;
      Bs[c4 * 4 + 2][row] = b.z; Bs[c4 * 4 + 3][row] = b.w;
    }
    __syncthreads();
#pragma unroll
    for (int kk = 0; kk < 16; ++kk) {
      float a[8], b[8];
#pragma unroll
      for (int p = 0; p < 4; ++p) {
        float2 t2 = *(const float2*)&As[kk][ty * 8 + p * 2];
        a[p * 2] = t2.x; a[p * 2 + 1] = t2.y;
        float2 u2 = *(const float2*)&Bs[kk][tx * 8 + p * 2];
        b[p * 2] = u2.x; b[p * 2 + 1] = u2.y;
      }
#pragma unroll
      for (int i = 0; i < 8; ++i)
#pragma unroll
        for (int j = 0; j < 8; ++j)
          acc[i][j] = fmaf(a[i], b[j], acc[i][j]);
    }
    __syncthreads();
  }
#pragma unroll
  for (int i = 0; i < 8; ++i) {
    int m = m0 + ty * 8 + i;
#pragma unroll
    for (int j = 0; j < 8; ++j) {
      int n = n0 + tx * 8 + j;
      if (n < N) {
        float v = acc[i][j];
        float res;
        if (EPI == 0) {
          res = v;
        } else if (EPI == 1) {
          res = tanhf(v);
        } else if (EPI == 2) {
          res = expf(-expf(v + bias[n]));
        } else {
          float xv = ex[(size_t)m * HID + n];
          int t = m & (TT - 1);
          float xs = t ? ex[(size_t)(m - 1) * HID + n] : 0.f;
          res = xv + (xs - xv) * (v + bias[n]);
        }
        C[(size_t)m * ldc + n] = res;
      }
    }
  }
}

// ---------------- c[b,h,t] = sum_dk r*u*k ----------------
__global__ __launch_bounds__(256) void calc_c(const float* __restrict__ r,
    const float* __restrict__ k, const float* __restrict__ u,
    float* __restrict__ c) {
  int idx = blockIdx.x * 4 + (threadIdx.x >> 6);   // (b*NH+h)*TT + t
  int lane = threadIdx.x & 63;
  int t = idx & (TT - 1);
  int bh = idx >> 11;
  int h = bh & (NH - 1);
  int b = bh >> 2;
  const float* rp = r + (size_t)(b * TT + t) * KD + h * DK;
  const float* kp = k + (size_t)(b * TT + t) * KD + h * DK;
  const float* up = u + h * DK;
  float2 rv = *(const float2*)&rp[lane * 2];
  float2 kv = *(const float2*)&kp[lane * 2];
  float2 uv = *(const float2*)&up[lane * 2];
  float p = rv.x * uv.x * kv.x + rv.y * uv.y * kv.y;
#pragma unroll
  for (int off = 32; off > 0; off >>= 1) p += __shfl_xor(p, off);
  if (lane == 0) c[idx] = p;
}

// ---------------- scan v2: grid = 16 bh x 16 dv-chunks; thread = (dv, dk-slice of 8) ----
// S[dk,dv] columns are independent across dv; dk reduced across 16 lanes via shfl.
__global__ __launch_bounds__(256) void scan2_kernel(
    const float* __restrict__ r, const float* __restrict__ k,
    const float* __restrict__ d, const float* __restrict__ v,
    const float* __restrict__ c, float* __restrict__ o) {
  const int bh = blockIdx.x >> 4;          // 0..15
  const int chunk = blockIdx.x & 15;       // dv chunk of 16
  const int b = bh >> 2, h = bh & (NH - 1);
  const int dkg = threadIdx.x & 15;        // dk group 0..15
  const int dvi = threadIdx.x >> 4;        // dv within chunk 0..15
  const int dv = chunk * 16 + dvi;

  const int i0 = dkg * 4;                  // dk slice part 1
  const int i1 = 64 + dkg * 4;             // dk slice part 2

  const float* rp = r + (size_t)(b * TT) * KD + h * DK;
  const float* kp = k + (size_t)(b * TT) * KD + h * DK;
  const float* dp = d + (size_t)(b * TT) * KD + h * DK;
  const float* vp = v + (size_t)(b * TT) * VD + h * DV + dv;
  const float* cp = c + (size_t)bh * TT;
  float* op = o + (size_t)(b * TT) * VD + h * DV + dv;

  float S[8];
#pragma unroll
  for (int i = 0; i < 8; ++i) S[i] = 0.f;

  for (int t = 0; t < TT; ++t) {
    float4 r0 = *(const float4*)(rp + i0);
    float4 r1 = *(const float4*)(rp + i1);
    float4 k0 = *(const float4*)(kp + i0);
    float4 k1 = *(const float4*)(kp + i1);
    float4 d0 = *(const float4*)(dp + i0);
    float4 d1 = *(const float4*)(dp + i1);
    float vt = *vp;
    float ct = cp[t];

    // partial output: r . S (pre-update state)
    float pa = r0.x * S[0];
    float pb = r1.x * S[4];
    pa = fmaf(r0.y, S[1], pa);
    pb = fmaf(r1.y, S[5], pb);
    pa = fmaf(r0.z, S[2], pa);
    pb = fmaf(r1.z, S[6], pb);
    pa = fmaf(r0.w, S[3], pa);
    pb = fmaf(r1.w, S[7], pb);

    // state update: S = d*S + k*vt
    S[0] = fmaf(d0.x, S[0], k0.x * vt);
    S[1] = fmaf(d0.y, S[1], k0.y * vt);
    S[2] = fmaf(d0.z, S[2], k0.z * vt);
    S[3] = fmaf(d0.w, S[3], k0.w * vt);
    S[4] = fmaf(d1.x, S[4], k1.x * vt);
    S[5] = fmaf(d1.y, S[5], k1.y * vt);
    S[6] = fmaf(d1.z, S[6], k1.z * vt);
    S[7] = fmaf(d1.w, S[7], k1.w * vt);

    float p = pa + pb;
    // reduce over the 16 dk-group lanes (stays inside 16-lane group)
    p += __shfl_xor(p, 1);
    p += __shfl_xor(p, 2);
    p += __shfl_xor(p, 4);
    p += __shfl_xor(p, 8);
    if (dkg == 0) *op = fmaf(ct, vt, p);

    rp += KD; kp += KD; dp += KD; vp += VD; op += VD;
  }
}

// ---------------- GroupNorm (per b,t,h over DV) + gn affine + silu(g) gate ----------------
__global__ __launch_bounds__(256) void gn_gate(const float* __restrict__ o,
    const float* __restrict__ g, const float* __restrict__ gnw,
    const float* __restrict__ gnb, float* __restrict__ out) {
  int tok = blockIdx.x;
  int tid = threadIdx.x;
  __shared__ float s1[4], s2[4];
  for (int h = 0; h < NH; ++h) {
    int col = h * DV + tid;
    float val = o[(size_t)tok * VD + col];
    float a = val, bsq = val * val;
#pragma unroll
    for (int off = 32; off > 0; off >>= 1) {
      a += __shfl_xor(a, off);
      bsq += __shfl_xor(bsq, off);
    }
    int wid = tid >> 6;
    if ((tid & 63) == 0) { s1[wid] = a; s2[wid] = bsq; }
    __syncthreads();
    float S1 = s1[0] + s1[1] + s1[2] + s1[3];
    float S2 = s2[0] + s2[1] + s2[2] + s2[3];
    float mean = S1 * (1.f / DV);
    float var = S2 * (1.f / DV) - mean * mean;
    float xn = (val - mean) * rsqrtf(var + 1e-5f);
    float gv = g[(size_t)tok * VD + col];
    float sig = gv / (1.f + expf(-gv));          // silu(g) = g*sigmoid(g)
    out[(size_t)tok * VD + col] = (xn * gnw[col] + gnb[col]) * sig;
    __syncthreads();
  }
}

extern "C" void kernel_launch(void* const* d_in, const int* in_sizes, int n_in,
                              void* d_out, int out_size, void* d_ws, size_t ws_size,
                              hipStream_t stream) {
  const float* x      = (const float*)d_in[0];
  const float* mu0    = (const float*)d_in[1];
  const float* W_x0   = (const float*)d_in[2];
  const float* W_x2   = (const float*)d_in[3];
  const float* x_bias = (const float*)d_in[4];
  const float* W_r    = (const float*)d_in[5];
  const float* W_w1   = (const float*)d_in[6];
  const float* W_w2   = (const float*)d_in[7];
  const float* b_w2   = (const float*)d_in[8];
  const float* W_k    = (const float*)d_in[9];
  const float* W_v    = (const float*)d_in[10];
  const float* W_g    = (const float*)d_in[11];
  const float* bonus  = (const float*)d_in[12];
  const float* gnw    = (const float*)d_in[13];
  const float* gnb    = (const float*)d_in[14];
  const float* W_o    = (const float*)d_in[15];
  float* out = (float*)d_out;

  float* ws = (float*)d_ws;
  size_t off = 0;
  float* buf  = ws + off; off += (size_t)BT * HID;   // reused: xz, lerped inputs, gated out
  float* xp   = ws + off; off += (size_t)BT * R5;
  float* rb   = ws + off; off += (size_t)BT * KD;
  float* db   = ws + off; off += (size_t)BT * KD;
  float* kb   = ws + off; off += (size_t)BT * KD;
  float* vb   = ws + off; off += (size_t)BT * VD;
  float* gb   = ws + off; off += (size_t)BT * VD;
  float* wlow = ws + off; off += (size_t)BT * GLR;
  float* cb   = ws + off; off += (size_t)BB * NH * TT;
  float* ob   = ws + off; off += (size_t)BT * VD;

  dim3 blk(256);

  // xz = lerp(x, mu0); xp = tanh(xz @ W_x0^T)
  lerp0_kernel<<<dim3(BT * HID / 1024), blk, 0, stream>>>(x, mu0, buf);
  gemm_bt<1><<<dim3(2, 64), blk, 0, stream>>>(buf, HID, W_x0, HID, xp, R5,
                                              BT, R5, HID, nullptr, nullptr);
  // slot 0 -> r
  gemm_bt<3><<<dim3(8, 64), blk, 0, stream>>>(xp + 0 * RR, R5, W_x2 + 0 * RR, R5, buf, HID,
                                              BT, HID, RR, x_bias + 0 * HID, x);
  gemm_bt<0><<<dim3(4, 64), blk, 0, stream>>>(buf, HID, W_r, HID, rb, KD,
                                              BT, KD, HID, nullptr, nullptr);
  // slot 1 -> w (lora down+tanh, up+bias, then decay = exp(-exp(w)))
  gemm_bt<3><<<dim3(8, 64), blk, 0, stream>>>(xp + 1 * RR, R5, W_x2 + 1 * RR, R5, buf, HID,
                                              BT, HID, RR, x_bias + 1 * HID, x);
  gemm_bt<1><<<dim3(1, 64), blk, 0, stream>>>(buf, HID, W_w1, HID, wlow, GLR,
                                              BT, GLR, HID, nullptr, nullptr);
  gemm_bt<2><<<dim3(4, 64), blk, 0, stream>>>(wlow, GLR, W_w2, GLR, db, KD,
                                              BT, KD, GLR, b_w2, nullptr);
  // slot 2 -> k
  gemm_bt<3><<<dim3(8, 64), blk, 0, stream>>>(xp + 2 * RR, R5, W_x2 + 2 * RR, R5, buf, HID,
                                              BT, HID, RR, x_bias + 2 * HID, x);
  gemm_bt<0><<<dim3(4, 64), blk, 0, stream>>>(buf, HID, W_k, HID, kb, KD,
                                              BT, KD, HID, nullptr, nullptr);
  // slot 3 -> v
  gemm_bt<3><<<dim3(8, 64), blk, 0, stream>>>(xp + 3 * RR, R5, W_x2 + 3 * RR, R5, buf, HID,
                                              BT, HID, RR, x_bias + 3 * HID, x);
  gemm_bt<0><<<dim3(8, 64), blk, 0, stream>>>(buf, HID, W_v, HID, vb, VD,
                                              BT, VD, HID, nullptr, nullptr);
  // slot 4 -> g
  gemm_bt<3><<<dim3(8, 64), blk, 0, stream>>>(xp + 4 * RR, R5, W_x2 + 4 * RR, R5, buf, HID,
                                              BT, HID, RR, x_bias + 4 * HID, x);
  gemm_bt<0><<<dim3(8, 64), blk, 0, stream>>>(buf, HID, W_g, HID, gb, VD,
                                              BT, VD, HID, nullptr, nullptr);

  // bonus scalar, scan (parallel over dv), groupnorm+gate, final projection
  calc_c<<<dim3(BB * NH * TT / 4), blk, 0, stream>>>(rb, kb, bonus, cb);
  scan2_kernel<<<dim3(BB * NH * 16), blk, 0, stream>>>(rb, kb, db, vb, cb, ob);
  gn_gate<<<dim3(BT), blk, 0, stream>>>(ob, gb, gnw, gnb, buf);
  gemm_bt<0><<<dim3(8, 64), blk, 0, stream>>>(buf, HID, W_o, HID, out, HID,
                                              BT, HID, HID, nullptr, nullptr);
}

// Round 4
// 2689.914 us; speedup vs baseline: 4.5521x; 1.1225x over previous
//
#include <hip/hip_runtime.h>
#include <hip/hip_bf16.h>

#define BB 4
#define TT 2048
#define HID 1024
#define NH 4
#define KD 512
#define VD 1024
#define DK 128
#define DV 256
#define RR 32
#define R5 160
#define GLR 64
#define BT (BB*TT)

// ---------------- elementwise: xz = x + (shift(x) - x) * mu0 ----------------
__global__ __launch_bounds__(256) void lerp0_kernel(const float* __restrict__ x,
    const float* __restrict__ mu0, float* __restrict__ out) {
  size_t i = (size_t)blockIdx.x * 256 + threadIdx.x;     // float4 index
  const int ncol4 = HID / 4;
  int c4 = (int)(i % ncol4);
  size_t tok = i / ncol4;
  int t = (int)(tok & (TT - 1));
  float4 xv = ((const float4*)x)[i];
  float4 m  = ((const float4*)mu0)[c4];
  float4 xs = make_float4(0.f, 0.f, 0.f, 0.f);
  if (t) xs = ((const float4*)x)[i - ncol4];
  float4 r;
  r.x = xv.x + (xs.x - xv.x) * m.x;
  r.y = xv.y + (xs.y - xv.y) * m.y;
  r.z = xv.z + (xs.z - xv.z) * m.z;
  r.w = xv.w + (xs.w - xv.w) * m.w;
  ((float4*)out)[i] = r;
}

// ---------------- generic fp32 GEMM: C = epi(X @ W^T) ----------------
// X: (M,K) row stride lda; W: (N,K) row stride ldb; C: (M,N) row stride ldc.
// EPI: 0 none | 1 tanh | 2 exp(-exp(v + bias[n])) | 3 lerp: x + (shift-x)*(v+bias[n])
template<int EPI>
__global__ __launch_bounds__(256) void gemm_bt(
    const float* __restrict__ X, int lda,
    const float* __restrict__ W, int ldb,
    float* __restrict__ C, int ldc,
    int M, int N, int K,
    const float* __restrict__ bias,
    const float* __restrict__ ex) {
  __shared__ float As[16][132];
  __shared__ float Bs[16][132];
  const int tid = threadIdx.x;
  const int tx = tid & 15;
  const int ty = tid >> 4;
  const int m0 = blockIdx.y * 128;
  const int n0 = blockIdx.x * 128;
  float acc[8][8];
#pragma unroll
  for (int i = 0; i < 8; ++i)
#pragma unroll
    for (int j = 0; j < 8; ++j) acc[i][j] = 0.f;

  for (int k0 = 0; k0 < K; k0 += 16) {
#pragma unroll
    for (int s = 0; s < 2; ++s) {
      int q = s * 256 + tid;
      int row = q >> 2;
      int c4 = q & 3;
      float4 a = *(const float4*)&X[(size_t)(m0 + row) * lda + k0 + c4 * 4];
      As[c4 * 4 + 0][row] = a.x; As[c4 * 4 + 1][row] = a.y;
      As[c4 * 4 + 2][row] = a.z; As[c4 * 4 + 3][row] = a.w;
      int wr = n0 + row;
      float4 b = make_float4(0.f, 0.f, 0.f, 0.f);
      if (wr < N) b = *(const float4*)&W[(size_t)wr * ldb + k0 + c4 * 4];
      Bs[c4 * 4 + 0][row] = b.x; Bs[c4 * 4 + 1][row] = b.y;
      Bs[c4 * 4 + 2][row] = b.z; Bs[c4 * 4 + 3][row] = b.w;
    }
    __syncthreads();
#pragma unroll
    for (int kk = 0; kk < 16; ++kk) {
      float a[8], b[8];
#pragma unroll
      for (int p = 0; p < 4; ++p) {
        float2 t2 = *(const float2*)&As[kk][ty * 8 + p * 2];
        a[p * 2] = t2.x; a[p * 2 + 1] = t2.y;
        float2 u2 = *(const float2*)&Bs[kk][tx * 8 + p * 2];
        b[p * 2] = u2.x; b[p * 2 + 1] = u2.y;
      }
#pragma unroll
      for (int i = 0; i < 8; ++i)
#pragma unroll
        for (int j = 0; j < 8; ++j)
          acc[i][j] = fmaf(a[i], b[j], acc[i][j]);
    }
    __syncthreads();
  }
#pragma unroll
  for (int i = 0; i < 8; ++i) {
    int m = m0 + ty * 8 + i;
#pragma unroll
    for (int j = 0; j < 8; ++j) {
      int n = n0 + tx * 8 + j;
      if (n < N) {
        float v = acc[i][j];
        float res;
        if (EPI == 0) {
          res = v;
        } else if (EPI == 1) {
          res = tanhf(v);
        } else if (EPI == 2) {
          res = expf(-expf(v + bias[n]));
        } else {
          float xv = ex[(size_t)m * HID + n];
          int t = m & (TT - 1);
          float xs = t ? ex[(size_t)(m - 1) * HID + n] : 0.f;
          res = xv + (xs - xv) * (v + bias[n]);
        }
        C[(size_t)m * ldc + n] = res;
      }
    }
  }
}

// ---------------- c[b,h,t] = sum_dk r*u*k ----------------
__global__ __launch_bounds__(256) void calc_c(const float* __restrict__ r,
    const float* __restrict__ k, const float* __restrict__ u,
    float* __restrict__ c) {
  int idx = blockIdx.x * 4 + (threadIdx.x >> 6);   // (b*NH+h)*TT + t
  int lane = threadIdx.x & 63;
  int t = idx & (TT - 1);
  int bh = idx >> 11;
  int h = bh & (NH - 1);
  int b = bh >> 2;
  const float* rp = r + (size_t)(b * TT + t) * KD + h * DK;
  const float* kp = k + (size_t)(b * TT + t) * KD + h * DK;
  const float* up = u + h * DK;
  float2 rv = *(const float2*)&rp[lane * 2];
  float2 kv = *(const float2*)&kp[lane * 2];
  float2 uv = *(const float2*)&up[lane * 2];
  float p = rv.x * uv.x * kv.x + rv.y * uv.y * kv.y;
#pragma unroll
  for (int off = 32; off > 0; off >>= 1) p += __shfl_xor(p, off);
  if (lane == 0) c[idx] = p;
}

// ---------------- scan v3: 512 blocks (16 bh x 32 dv-chunks); thread = (dv, dk-slice of 4) ----
// 2 blocks/CU -> 2 waves/SIMD; explicit next-step prefetch so the only
// loop-carried chain is the S-update FMA. dk reduced across 32 lanes via shfl.
__global__ __launch_bounds__(256) void scan3_kernel(
    const float* __restrict__ r, const float* __restrict__ k,
    const float* __restrict__ d, const float* __restrict__ v,
    const float* __restrict__ c, float* __restrict__ o) {
  const int bh = blockIdx.x >> 5;          // 0..15
  const int chunk = blockIdx.x & 31;       // dv chunk of 8
  const int b = bh >> 2, h = bh & (NH - 1);
  const int dkg = threadIdx.x & 31;        // dk group 0..31
  const int dvi = threadIdx.x >> 5;        // dv within chunk 0..7
  const int dv = chunk * 8 + dvi;

  const float* rp = r + (size_t)(b * TT) * KD + h * DK + dkg * 4;
  const float* kp = k + (size_t)(b * TT) * KD + h * DK + dkg * 4;
  const float* dp = d + (size_t)(b * TT) * KD + h * DK + dkg * 4;
  const float* vp = v + (size_t)(b * TT) * VD + h * DV + dv;
  const float* cp = c + (size_t)bh * TT;
  float* op = o + (size_t)(b * TT) * VD + h * DV + dv;

  float S0 = 0.f, S1 = 0.f, S2 = 0.f, S3 = 0.f;

  // prime the pipeline: t = 0
  float4 rv = *(const float4*)rp;
  float4 kv = *(const float4*)kp;
  float4 dq = *(const float4*)dp;
  float vt = *vp;
  float ct = cp[0];

#pragma unroll 2
  for (int t = 0; t < TT; ++t) {
    // prefetch t+1 (last iteration over-reads into the adjacent ws buffer — allocated, unused)
    float4 rn = *(const float4*)(rp + KD);
    float4 kn = *(const float4*)(kp + KD);
    float4 dn = *(const float4*)(dp + KD);
    float vn = vp[VD];
    float cn = cp[t + 1];

    // partial output: r . S (pre-update state)
    float p = rv.x * S0;
    p = fmaf(rv.y, S1, p);
    p = fmaf(rv.z, S2, p);
    p = fmaf(rv.w, S3, p);

    // state update: S = d*S + k*vt
    S0 = fmaf(dq.x, S0, kv.x * vt);
    S1 = fmaf(dq.y, S1, kv.y * vt);
    S2 = fmaf(dq.z, S2, kv.z * vt);
    S3 = fmaf(dq.w, S3, kv.w * vt);

    // reduce over the 32 dk-group lanes (stays inside 32-lane half-wave)
    p += __shfl_xor(p, 1);
    p += __shfl_xor(p, 2);
    p += __shfl_xor(p, 4);
    p += __shfl_xor(p, 8);
    p += __shfl_xor(p, 16);
    if (dkg == 0) *op = fmaf(ct, vt, p);

    rv = rn; kv = kn; dq = dn; vt = vn; ct = cn;
    rp += KD; kp += KD; dp += KD; vp += VD; op += VD;
  }
}

// ---------------- GroupNorm (per b,t,h over DV) + gn affine + silu(g) gate ----------------
__global__ __launch_bounds__(256) void gn_gate(const float* __restrict__ o,
    const float* __restrict__ g, const float* __restrict__ gnw,
    const float* __restrict__ gnb, float* __restrict__ out) {
  int tok = blockIdx.x;
  int tid = threadIdx.x;
  __shared__ float s1[4], s2[4];
  for (int h = 0; h < NH; ++h) {
    int col = h * DV + tid;
    float val = o[(size_t)tok * VD + col];
    float a = val, bsq = val * val;
#pragma unroll
    for (int off = 32; off > 0; off >>= 1) {
      a += __shfl_xor(a, off);
      bsq += __shfl_xor(bsq, off);
    }
    int wid = tid >> 6;
    if ((tid & 63) == 0) { s1[wid] = a; s2[wid] = bsq; }
    __syncthreads();
    float S1 = s1[0] + s1[1] + s1[2] + s1[3];
    float S2 = s2[0] + s2[1] + s2[2] + s2[3];
    float mean = S1 * (1.f / DV);
    float var = S2 * (1.f / DV) - mean * mean;
    float xn = (val - mean) * rsqrtf(var + 1e-5f);
    float gv = g[(size_t)tok * VD + col];
    float sig = gv / (1.f + expf(-gv));          // silu(g) = g*sigmoid(g)
    out[(size_t)tok * VD + col] = (xn * gnw[col] + gnb[col]) * sig;
    __syncthreads();
  }
}

extern "C" void kernel_launch(void* const* d_in, const int* in_sizes, int n_in,
                              void* d_out, int out_size, void* d_ws, size_t ws_size,
                              hipStream_t stream) {
  const float* x      = (const float*)d_in[0];
  const float* mu0    = (const float*)d_in[1];
  const float* W_x0   = (const float*)d_in[2];
  const float* W_x2   = (const float*)d_in[3];
  const float* x_bias = (const float*)d_in[4];
  const float* W_r    = (const float*)d_in[5];
  const float* W_w1   = (const float*)d_in[6];
  const float* W_w2   = (const float*)d_in[7];
  const float* b_w2   = (const float*)d_in[8];
  const float* W_k    = (const float*)d_in[9];
  const float* W_v    = (const float*)d_in[10];
  const float* W_g    = (const float*)d_in[11];
  const float* bonus  = (const float*)d_in[12];
  const float* gnw    = (const float*)d_in[13];
  const float* gnb    = (const float*)d_in[14];
  const float* W_o    = (const float*)d_in[15];
  float* out = (float*)d_out;

  float* ws = (float*)d_ws;
  size_t off = 0;
  float* buf  = ws + off; off += (size_t)BT * HID;   // reused: xz, lerped inputs, gated out
  float* xp   = ws + off; off += (size_t)BT * R5;
  float* rb   = ws + off; off += (size_t)BT * KD;
  float* db   = ws + off; off += (size_t)BT * KD;
  float* kb   = ws + off; off += (size_t)BT * KD;
  float* vb   = ws + off; off += (size_t)BT * VD;
  float* gb   = ws + off; off += (size_t)BT * VD;
  float* wlow = ws + off; off += (size_t)BT * GLR;
  float* cb   = ws + off; off += (size_t)BB * NH * TT;
  float* ob   = ws + off; off += (size_t)BT * VD;

  dim3 blk(256);

  // xz = lerp(x, mu0); xp = tanh(xz @ W_x0^T)
  lerp0_kernel<<<dim3(BT * HID / 1024), blk, 0, stream>>>(x, mu0, buf);
  gemm_bt<1><<<dim3(2, 64), blk, 0, stream>>>(buf, HID, W_x0, HID, xp, R5,
                                              BT, R5, HID, nullptr, nullptr);
  // slot 0 -> r
  gemm_bt<3><<<dim3(8, 64), blk, 0, stream>>>(xp + 0 * RR, R5, W_x2 + 0 * RR, R5, buf, HID,
                                              BT, HID, RR, x_bias + 0 * HID, x);
  gemm_bt<0><<<dim3(4, 64), blk, 0, stream>>>(buf, HID, W_r, HID, rb, KD,
                                              BT, KD, HID, nullptr, nullptr);
  // slot 1 -> w (lora down+tanh, up+bias, then decay = exp(-exp(w)))
  gemm_bt<3><<<dim3(8, 64), blk, 0, stream>>>(xp + 1 * RR, R5, W_x2 + 1 * RR, R5, buf, HID,
                                              BT, HID, RR, x_bias + 1 * HID, x);
  gemm_bt<1><<<dim3(1, 64), blk, 0, stream>>>(buf, HID, W_w1, HID, wlow, GLR,
                                              BT, GLR, HID, nullptr, nullptr);
  gemm_bt<2><<<dim3(4, 64), blk, 0, stream>>>(wlow, GLR, W_w2, GLR, db, KD,
                                              BT, KD, GLR, b_w2, nullptr);
  // slot 2 -> k
  gemm_bt<3><<<dim3(8, 64), blk, 0, stream>>>(xp + 2 * RR, R5, W_x2 + 2 * RR, R5, buf, HID,
                                              BT, HID, RR, x_bias + 2 * HID, x);
  gemm_bt<0><<<dim3(4, 64), blk, 0, stream>>>(buf, HID, W_k, HID, kb, KD,
                                              BT, KD, HID, nullptr, nullptr);
  // slot 3 -> v
  gemm_bt<3><<<dim3(8, 64), blk, 0, stream>>>(xp + 3 * RR, R5, W_x2 + 3 * RR, R5, buf, HID,
                                              BT, HID, RR, x_bias + 3 * HID, x);
  gemm_bt<0><<<dim3(8, 64), blk, 0, stream>>>(buf, HID, W_v, HID, vb, VD,
                                              BT, VD, HID, nullptr, nullptr);
  // slot 4 -> g
  gemm_bt<3><<<dim3(8, 64), blk, 0, stream>>>(xp + 4 * RR, R5, W_x2 + 4 * RR, R5, buf, HID,
                                              BT, HID, RR, x_bias + 4 * HID, x);
  gemm_bt<0><<<dim3(8, 64), blk, 0, stream>>>(buf, HID, W_g, HID, gb, VD,
                                              BT, VD, HID, nullptr, nullptr);

  // bonus scalar, scan (parallel over dv, prefetched), groupnorm+gate, final projection
  calc_c<<<dim3(BB * NH * TT / 4), blk, 0, stream>>>(rb, kb, bonus, cb);
  scan3_kernel<<<dim3(BB * NH * 32), blk, 0, stream>>>(rb, kb, db, vb, cb, ob);
  gn_gate<<<dim3(BT), blk, 0, stream>>>(ob, gb, gnw, gnb, buf);
  gemm_bt<0><<<dim3(8, 64), blk, 0, stream>>>(buf, HID, W_o, HID, out, HID,
                                              BT, HID, HID, nullptr, nullptr);
}

// Round 7
// 1741.851 us; speedup vs baseline: 7.0298x; 1.5443x over previous
//
#include <hip/hip_runtime.h>
#include <hip/hip_bf16.h>

#define BB 4
#define TT 2048
#define HID 1024
#define NH 4
#define KD 512
#define VD 1024
#define DK 128
#define DV 256
#define RR 32
#define R5 160
#define GLR 64
#define BT (BB*TT)

typedef __attribute__((ext_vector_type(8))) short short8v;
typedef __attribute__((ext_vector_type(4))) float float4v;

__device__ __forceinline__ unsigned short f2bf(float f) {
  union { float f; unsigned u; } v; v.f = f;
  unsigned r = v.u + 0x7FFF + ((v.u >> 16) & 1);   // RNE
  return (unsigned short)(r >> 16);
}
__device__ __forceinline__ float bf2f(unsigned short h) {
  union { unsigned u; float f; } v; v.u = ((unsigned)h) << 16; return v.f;
}

__device__ __forceinline__ void gload_lds16(const unsigned short* g, unsigned short* l) {
  __builtin_amdgcn_global_load_lds(
      (const __attribute__((address_space(1))) unsigned int*)g,
      (__attribute__((address_space(3))) unsigned int*)l, 16, 0, 0);
}

// ---------------- weight fp32 -> bf16 hi+lo split ----------------
__global__ __launch_bounds__(256) void conv_split(const float* __restrict__ src,
    unsigned short* __restrict__ hi, unsigned short* __restrict__ lo, int n4) {
  int i = blockIdx.x * 256 + threadIdx.x;
  if (i >= n4) return;
  float4 v = ((const float4*)src)[i];
  ushort4 h, l;
  h.x = f2bf(v.x); l.x = f2bf(v.x - bf2f(h.x));
  h.y = f2bf(v.y); l.y = f2bf(v.y - bf2f(h.y));
  h.z = f2bf(v.z); l.z = f2bf(v.z - bf2f(h.z));
  h.w = f2bf(v.w); l.w = f2bf(v.w - bf2f(h.w));
  ((ushort4*)hi)[i] = h; ((ushort4*)lo)[i] = l;
}

// W_x0 (160,1024) -> padded (256,1024) bf16 (hi only), zero rows >= 160
__global__ __launch_bounds__(256) void conv_bf16_pad(const float* __restrict__ src,
    unsigned short* __restrict__ dst) {
  int i = blockIdx.x * 256 + threadIdx.x;          // float4 index over 256*1024
  int row = i >> 8;
  ushort4 o; o.x = o.y = o.z = o.w = 0;
  if (row < R5) {
    float4 v = ((const float4*)src)[i];
    o.x = f2bf(v.x); o.y = f2bf(v.y); o.z = f2bf(v.z); o.w = f2bf(v.w);
  }
  ((ushort4*)dst)[i] = o;
}

// ---------------- elementwise: xz = x + (shift(x) - x) * mu0 -> bf16 ----------------
__global__ __launch_bounds__(256) void lerp0_kernel(const float* __restrict__ x,
    const float* __restrict__ mu0, unsigned short* __restrict__ out) {
  size_t i = (size_t)blockIdx.x * 256 + threadIdx.x;     // float4 index
  const int ncol4 = HID / 4;
  int c4 = (int)(i % ncol4);
  size_t tok = i / ncol4;
  int t = (int)(tok & (TT - 1));
  float4 xv = ((const float4*)x)[i];
  float4 m  = ((const float4*)mu0)[c4];
  float4 xs = make_float4(0.f, 0.f, 0.f, 0.f);
  if (t) xs = ((const float4*)x)[i - ncol4];
  ushort4 r;
  r.x = f2bf(xv.x + (xs.x - xv.x) * m.x);
  r.y = f2bf(xv.y + (xs.y - xv.y) * m.y);
  r.z = f2bf(xv.z + (xs.z - xv.z) * m.z);
  r.w = f2bf(xv.w + (xs.w - xv.w) * m.w);
  ((ushort4*)out)[i] = r;
}

// ---------------- plain bf16 MFMA GEMM (xp only): C = epi(A @ B^T), fp32 out ----------------
template<int EPI>
__global__ __launch_bounds__(256) void gemm_mfma(
    const unsigned short* __restrict__ A,
    const unsigned short* __restrict__ B,
    float* __restrict__ C, int ldc, int N, int K) {
  __shared__ unsigned short As[128 * 32];
  __shared__ unsigned short Bs[128 * 32];
  const int tid = threadIdx.x;
  const int l = tid & 63;
  const int w = tid >> 6;
  const int m0 = blockIdx.y * 128;
  const int n0 = blockIdx.x * 128;
  const int wr = (w >> 1) * 64;
  const int wc = (w & 1) * 64;

  float4v acc[4][4];
#pragma unroll
  for (int i = 0; i < 4; ++i)
#pragma unroll
    for (int j = 0; j < 4; ++j) acc[i][j] = (float4v){0.f, 0.f, 0.f, 0.f};

  const int c0 = w * 64 + l;
  const int c1 = 256 + c0;
  const unsigned short* gA0 = A + (size_t)(m0 + (c0 >> 2)) * K + (c0 & 3) * 8;
  const unsigned short* gA1 = A + (size_t)(m0 + (c1 >> 2)) * K + (c1 & 3) * 8;
  const unsigned short* gB0 = B + (size_t)(n0 + (c0 >> 2)) * K + (c0 & 3) * 8;
  const unsigned short* gB1 = B + (size_t)(n0 + (c1 >> 2)) * K + (c1 & 3) * 8;
  unsigned short* lA0 = &As[(w * 64) * 8];
  unsigned short* lA1 = &As[(256 + w * 64) * 8];
  unsigned short* lB0 = &Bs[(w * 64) * 8];
  unsigned short* lB1 = &Bs[(256 + w * 64) * 8];

  const int arow = (l & 15) * 32 + (l >> 4) * 8;

  for (int k0 = 0; k0 < K; k0 += 32) {
    gload_lds16(gA0, lA0);
    gload_lds16(gA1, lA1);
    gload_lds16(gB0, lB0);
    gload_lds16(gB1, lB1);
    gA0 += 32; gA1 += 32; gB0 += 32; gB1 += 32;
    __syncthreads();
    short8v a[4], b[4];
#pragma unroll
    for (int i = 0; i < 4; ++i)
      a[i] = *(const short8v*)&As[(wr + i * 16) * 32 + arow];
#pragma unroll
    for (int j = 0; j < 4; ++j)
      b[j] = *(const short8v*)&Bs[(wc + j * 16) * 32 + arow];
#pragma unroll
    for (int i = 0; i < 4; ++i)
#pragma unroll
      for (int j = 0; j < 4; ++j)
        acc[i][j] = __builtin_amdgcn_mfma_f32_16x16x32_bf16(a[i], b[j], acc[i][j], 0, 0, 0);
    __syncthreads();
  }

#pragma unroll
  for (int i = 0; i < 4; ++i) {
#pragma unroll
    for (int j = 0; j < 4; ++j) {
      int col = n0 + wc + j * 16 + (l & 15);
      if (col < N) {
#pragma unroll
        for (int q = 0; q < 4; ++q) {
          int row = m0 + wr + i * 16 + (l >> 4) * 4 + q;
          float v2 = acc[i][j][q];
          if (EPI == 1) v2 = tanhf(v2);
          C[(size_t)row * ldc + col] = v2;
        }
      }
    }
  }
}

// ---------------- split-bf16 3-pass MFMA GEMM: C = (Ah+Al) @ (Bh+Bl)^T, fp32 out ----
// Error ~2^-18 relative (fp32-class). A*: (M,K); B*: (N,K); C: (M,N).
__global__ __launch_bounds__(256) void gemm_mfma3(
    const unsigned short* __restrict__ Ah, const unsigned short* __restrict__ Al,
    const unsigned short* __restrict__ Bh, const unsigned short* __restrict__ Bl,
    float* __restrict__ C, int ldc, int N, int K) {
  __shared__ unsigned short AsH[128 * 32];
  __shared__ unsigned short AsL[128 * 32];
  __shared__ unsigned short BsH[128 * 32];
  __shared__ unsigned short BsL[128 * 32];
  const int tid = threadIdx.x;
  const int l = tid & 63;
  const int w = tid >> 6;
  const int m0 = blockIdx.y * 128;
  const int n0 = blockIdx.x * 128;
  const int wr = (w >> 1) * 64;
  const int wc = (w & 1) * 64;

  float4v acc[4][4];
#pragma unroll
  for (int i = 0; i < 4; ++i)
#pragma unroll
    for (int j = 0; j < 4; ++j) acc[i][j] = (float4v){0.f, 0.f, 0.f, 0.f};

  const int c0 = w * 64 + l;
  const int c1 = 256 + c0;
  const size_t oA0 = (size_t)(m0 + (c0 >> 2)) * K + (c0 & 3) * 8;
  const size_t oA1 = (size_t)(m0 + (c1 >> 2)) * K + (c1 & 3) * 8;
  const size_t oB0 = (size_t)(n0 + (c0 >> 2)) * K + (c0 & 3) * 8;
  const size_t oB1 = (size_t)(n0 + (c1 >> 2)) * K + (c1 & 3) * 8;
  const unsigned short* gAh0 = Ah + oA0; const unsigned short* gAh1 = Ah + oA1;
  const unsigned short* gAl0 = Al + oA0; const unsigned short* gAl1 = Al + oA1;
  const unsigned short* gBh0 = Bh + oB0; const unsigned short* gBh1 = Bh + oB1;
  const unsigned short* gBl0 = Bl + oB0; const unsigned short* gBl1 = Bl + oB1;
  unsigned short* lAh0 = &AsH[w * 512]; unsigned short* lAh1 = &AsH[2048 + w * 512];
  unsigned short* lAl0 = &AsL[w * 512]; unsigned short* lAl1 = &AsL[2048 + w * 512];
  unsigned short* lBh0 = &BsH[w * 512]; unsigned short* lBh1 = &BsH[2048 + w * 512];
  unsigned short* lBl0 = &BsL[w * 512]; unsigned short* lBl1 = &BsL[2048 + w * 512];

  const int arow = (l & 15) * 32 + (l >> 4) * 8;

  for (int k0 = 0; k0 < K; k0 += 32) {
    gload_lds16(gAh0, lAh0); gload_lds16(gAh1, lAh1);
    gload_lds16(gAl0, lAl0); gload_lds16(gAl1, lAl1);
    gload_lds16(gBh0, lBh0); gload_lds16(gBh1, lBh1);
    gload_lds16(gBl0, lBl0); gload_lds16(gBl1, lBl1);
    gAh0 += 32; gAh1 += 32; gAl0 += 32; gAl1 += 32;
    gBh0 += 32; gBh1 += 32; gBl0 += 32; gBl1 += 32;
    __syncthreads();
    short8v ah[4], al[4], bh[4], bl[4];
#pragma unroll
    for (int i = 0; i < 4; ++i) {
      ah[i] = *(const short8v*)&AsH[(wr + i * 16) * 32 + arow];
      al[i] = *(const short8v*)&AsL[(wr + i * 16) * 32 + arow];
    }
#pragma unroll
    for (int j = 0; j < 4; ++j) {
      bh[j] = *(const short8v*)&BsH[(wc + j * 16) * 32 + arow];
      bl[j] = *(const short8v*)&BsL[(wc + j * 16) * 32 + arow];
    }
#pragma unroll
    for (int i = 0; i < 4; ++i)
#pragma unroll
      for (int j = 0; j < 4; ++j) {
        acc[i][j] = __builtin_amdgcn_mfma_f32_16x16x32_bf16(ah[i], bh[j], acc[i][j], 0, 0, 0);
        acc[i][j] = __builtin_amdgcn_mfma_f32_16x16x32_bf16(al[i], bh[j], acc[i][j], 0, 0, 0);
        acc[i][j] = __builtin_amdgcn_mfma_f32_16x16x32_bf16(ah[i], bl[j], acc[i][j], 0, 0, 0);
      }
    __syncthreads();
  }

#pragma unroll
  for (int i = 0; i < 4; ++i) {
#pragma unroll
    for (int j = 0; j < 4; ++j) {
      int col = n0 + wc + j * 16 + (l & 15);
      if (col < N) {
#pragma unroll
        for (int q = 0; q < 4; ++q) {
          int row = m0 + wr + i * 16 + (l >> 4) * 4 + q;
          C[(size_t)row * ldc + col] = acc[i][j][q];
        }
      }
    }
  }
}

// ---------------- generic fp32 GEMM: C = epi(X @ W^T) ----------------
// EPI: 1 tanh | 2 exp(-exp(v + bias[n])) | 3 lerp: x + (shift-x)*(v+bias[n])
// OUT: 0 fp32 -> C0 ; 2 bf16 hi/lo pair -> C0,C1
template<int EPI, int OUT>
__global__ __launch_bounds__(256) void gemm_bt(
    const float* __restrict__ X, int lda,
    const float* __restrict__ W, int ldb,
    void* __restrict__ C0v, void* __restrict__ C1v, int ldc,
    int M, int N, int K,
    const float* __restrict__ bias,
    const float* __restrict__ ex) {
  __shared__ float As2[16][132];
  __shared__ float Bs2[16][132];
  const int tid = threadIdx.x;
  const int tx = tid & 15;
  const int ty = tid >> 4;
  const int m0 = blockIdx.y * 128;
  const int n0 = blockIdx.x * 128;
  float acc[8][8];
#pragma unroll
  for (int i = 0; i < 8; ++i)
#pragma unroll
    for (int j = 0; j < 8; ++j) acc[i][j] = 0.f;

  for (int k0 = 0; k0 < K; k0 += 16) {
#pragma unroll
    for (int s = 0; s < 2; ++s) {
      int q = s * 256 + tid;
      int row = q >> 2;
      int c4 = q & 3;
      float4 a = *(const float4*)&X[(size_t)(m0 + row) * lda + k0 + c4 * 4];
      As2[c4 * 4 + 0][row] = a.x; As2[c4 * 4 + 1][row] = a.y;
      As2[c4 * 4 + 2][row] = a.z; As2[c4 * 4 + 3][row] = a.w;
      int wr = n0 + row;
      float4 b = make_float4(0.f, 0.f, 0.f, 0.f);
      if (wr < N) b = *(const float4*)&W[(size_t)wr * ldb + k0 + c4 * 4];
      Bs2[c4 * 4 + 0][row] = b.x; Bs2[c4 * 4 + 1][row] = b.y;
      Bs2[c4 * 4 + 2][row] = b.z; Bs2[c4 * 4 + 3][row] = b.w;
    }
    __syncthreads();
#pragma unroll
    for (int kk = 0; kk < 16; ++kk) {
      float a[8], b[8];
#pragma unroll
      for (int p = 0; p < 4; ++p) {
        float2 t2 = *(const float2*)&As2[kk][ty * 8 + p * 2];
        a[p * 2] = t2.x; a[p * 2 + 1] = t2.y;
        float2 u2 = *(const float2*)&Bs2[kk][tx * 8 + p * 2];
        b[p * 2] = u2.x; b[p * 2 + 1] = u2.y;
      }
#pragma unroll
      for (int i = 0; i < 8; ++i)
#pragma unroll
        for (int j = 0; j < 8; ++j)
          acc[i][j] = fmaf(a[i], b[j], acc[i][j]);
    }
    __syncthreads();
  }
#pragma unroll
  for (int i = 0; i < 8; ++i) {
    int m = m0 + ty * 8 + i;
#pragma unroll
    for (int j = 0; j < 8; ++j) {
      int n = n0 + tx * 8 + j;
      if (n < N) {
        float v = acc[i][j];
        float res;
        if (EPI == 1) {
          res = tanhf(v);
        } else if (EPI == 2) {
          res = expf(-expf(v + bias[n]));
        } else {
          float xv = ex[(size_t)m * HID + n];
          int t = m & (TT - 1);
          float xs = t ? ex[(size_t)(m - 1) * HID + n] : 0.f;
          res = xv + (xs - xv) * (v + bias[n]);
        }
        size_t idx = (size_t)m * ldc + n;
        if (OUT == 0) {
          ((float*)C0v)[idx] = res;
        } else {
          unsigned short hv = f2bf(res);
          ((unsigned short*)C0v)[idx] = hv;
          ((unsigned short*)C1v)[idx] = f2bf(res - bf2f(hv));
        }
      }
    }
  }
}

// ---------------- c[b,h,t] = sum_dk r*u*k ----------------
__global__ __launch_bounds__(256) void calc_c(const float* __restrict__ r,
    const float* __restrict__ k, const float* __restrict__ u,
    float* __restrict__ c) {
  int idx = blockIdx.x * 4 + (threadIdx.x >> 6);   // (b*NH+h)*TT + t
  int lane = threadIdx.x & 63;
  int t = idx & (TT - 1);
  int bh = idx >> 11;
  int h = bh & (NH - 1);
  int b = bh >> 2;
  const float* rp = r + (size_t)(b * TT + t) * KD + h * DK;
  const float* kp = k + (size_t)(b * TT + t) * KD + h * DK;
  const float* up = u + h * DK;
  float2 rv = *(const float2*)&rp[lane * 2];
  float2 kv = *(const float2*)&kp[lane * 2];
  float2 uv = *(const float2*)&up[lane * 2];
  float p = rv.x * uv.x * kv.x + rv.y * uv.y * kv.y;
#pragma unroll
  for (int off = 32; off > 0; off >>= 1) p += __shfl_xor(p, off);
  if (lane == 0) c[idx] = p;
}

// ---------------- scan v3: 512 blocks (16 bh x 32 dv-chunks); thread = (dv, dk-slice of 4) ----
__global__ __launch_bounds__(256) void scan3_kernel(
    const float* __restrict__ r, const float* __restrict__ k,
    const float* __restrict__ d, const float* __restrict__ v,
    const float* __restrict__ c, float* __restrict__ o) {
  const int bh = blockIdx.x >> 5;          // 0..15
  const int chunk = blockIdx.x & 31;       // dv chunk of 8
  const int b = bh >> 2, h = bh & (NH - 1);
  const int dkg = threadIdx.x & 31;        // dk group 0..31
  const int dvi = threadIdx.x >> 5;        // dv within chunk 0..7
  const int dv = chunk * 8 + dvi;

  const float* rp = r + (size_t)(b * TT) * KD + h * DK + dkg * 4;
  const float* kp = k + (size_t)(b * TT) * KD + h * DK + dkg * 4;
  const float* dp = d + (size_t)(b * TT) * KD + h * DK + dkg * 4;
  const float* vp = v + (size_t)(b * TT) * VD + h * DV + dv;
  const float* cp = c + (size_t)bh * TT;
  float* op = o + (size_t)(b * TT) * VD + h * DV + dv;

  float S0 = 0.f, S1 = 0.f, S2 = 0.f, S3 = 0.f;

  float4 rv = *(const float4*)rp;
  float4 kv = *(const float4*)kp;
  float4 dq = *(const float4*)dp;
  float vt = *vp;
  float ct = cp[0];

#pragma unroll 2
  for (int t = 0; t < TT; ++t) {
    float4 rn = *(const float4*)(rp + KD);
    float4 kn = *(const float4*)(kp + KD);
    float4 dn = *(const float4*)(dp + KD);
    float vn = vp[VD];
    float cn = cp[t + 1];

    float p = rv.x * S0;
    p = fmaf(rv.y, S1, p);
    p = fmaf(rv.z, S2, p);
    p = fmaf(rv.w, S3, p);

    S0 = fmaf(dq.x, S0, kv.x * vt);
    S1 = fmaf(dq.y, S1, kv.y * vt);
    S2 = fmaf(dq.z, S2, kv.z * vt);
    S3 = fmaf(dq.w, S3, kv.w * vt);

    p += __shfl_xor(p, 1);
    p += __shfl_xor(p, 2);
    p += __shfl_xor(p, 4);
    p += __shfl_xor(p, 8);
    p += __shfl_xor(p, 16);
    if (dkg == 0) *op = fmaf(ct, vt, p);

    rv = rn; kv = kn; dq = dn; vt = vn; ct = cn;
    rp += KD; kp += KD; dp += KD; vp += VD; op += VD;
  }
}

// ---------------- GroupNorm + affine + silu(g) gate -> bf16 hi/lo ----------------
__global__ __launch_bounds__(256) void gn_gate(const float* __restrict__ o,
    const float* __restrict__ g, const float* __restrict__ gnw,
    const float* __restrict__ gnb, unsigned short* __restrict__ ohi,
    unsigned short* __restrict__ olo) {
  int tok = blockIdx.x;
  int tid = threadIdx.x;
  __shared__ float s1[4], s2[4];
  for (int h = 0; h < NH; ++h) {
    int col = h * DV + tid;
    float val = o[(size_t)tok * VD + col];
    float a = val, bsq = val * val;
#pragma unroll
    for (int off = 32; off > 0; off >>= 1) {
      a += __shfl_xor(a, off);
      bsq += __shfl_xor(bsq, off);
    }
    int wid = tid >> 6;
    if ((tid & 63) == 0) { s1[wid] = a; s2[wid] = bsq; }
    __syncthreads();
    float S1 = s1[0] + s1[1] + s1[2] + s1[3];
    float S2 = s2[0] + s2[1] + s2[2] + s2[3];
    float mean = S1 * (1.f / DV);
    float var = S2 * (1.f / DV) - mean * mean;
    float xn = (val - mean) * rsqrtf(var + 1e-5f);
    float gv = g[(size_t)tok * VD + col];
    float sig = gv / (1.f + expf(-gv));
    float res = (xn * gnw[col] + gnb[col]) * sig;
    unsigned short hv = f2bf(res);
    ohi[(size_t)tok * VD + col] = hv;
    olo[(size_t)tok * VD + col] = f2bf(res - bf2f(hv));
    __syncthreads();
  }
}

extern "C" void kernel_launch(void* const* d_in, const int* in_sizes, int n_in,
                              void* d_out, int out_size, void* d_ws, size_t ws_size,
                              hipStream_t stream) {
  const float* x      = (const float*)d_in[0];
  const float* mu0    = (const float*)d_in[1];
  const float* W_x0   = (const float*)d_in[2];
  const float* W_x2   = (const float*)d_in[3];
  const float* x_bias = (const float*)d_in[4];
  const float* W_r    = (const float*)d_in[5];
  const float* W_w1   = (const float*)d_in[6];
  const float* W_w2   = (const float*)d_in[7];
  const float* b_w2   = (const float*)d_in[8];
  const float* W_k    = (const float*)d_in[9];
  const float* W_v    = (const float*)d_in[10];
  const float* W_g    = (const float*)d_in[11];
  const float* bonus  = (const float*)d_in[12];
  const float* gnw    = (const float*)d_in[13];
  const float* gnb    = (const float*)d_in[14];
  const float* W_o    = (const float*)d_in[15];
  float* out = (float*)d_out;

  float* ws = (float*)d_ws;
  size_t off = 0;
  float* buf  = ws + off; off += (size_t)BT * HID;   // fp32: w-lerp, then reused as scan output
  float* xp   = ws + off; off += (size_t)BT * R5;
  float* rb   = ws + off; off += (size_t)BT * KD;
  float* db   = ws + off; off += (size_t)BT * KD;
  float* kb   = ws + off; off += (size_t)BT * KD;
  float* vb   = ws + off; off += (size_t)BT * VD;
  float* gb   = ws + off; off += (size_t)BT * VD;
  float* wlow = ws + off; off += (size_t)BT * GLR;
  float* cb   = ws + off; off += (size_t)BB * NH * TT;
  float* ob   = buf;                                  // reuse (buf free after w-path)
  unsigned short* us = (unsigned short*)(ws + off);
  size_t uoff = 0;
  unsigned short* ah   = us + uoff; uoff += (size_t)BT * HID;  // bf16 A hi (reused)
  unsigned short* al   = us + uoff; uoff += (size_t)BT * HID;  // bf16 A lo (reused)
  unsigned short* wx0p = us + uoff; uoff += (size_t)256 * HID; // padded W_x0 (hi only)
  unsigned short* wrh  = us + uoff; uoff += (size_t)KD * HID;
  unsigned short* wrl  = us + uoff; uoff += (size_t)KD * HID;
  unsigned short* wkh  = us + uoff; uoff += (size_t)KD * HID;
  unsigned short* wkl  = us + uoff; uoff += (size_t)KD * HID;
  unsigned short* wvh  = us + uoff; uoff += (size_t)VD * HID;
  unsigned short* wvl  = us + uoff; uoff += (size_t)VD * HID;
  unsigned short* wgh  = us + uoff; uoff += (size_t)VD * HID;
  unsigned short* wgl  = us + uoff; uoff += (size_t)VD * HID;
  unsigned short* woh  = us + uoff; uoff += (size_t)HID * VD;
  unsigned short* wol  = us + uoff; uoff += (size_t)HID * VD;

  dim3 blk(256);

  // weight conversions
  conv_bf16_pad<<<dim3(256 * HID / 1024), blk, 0, stream>>>(W_x0, wx0p);
  conv_split<<<dim3(KD * HID / 1024), blk, 0, stream>>>(W_r, wrh, wrl, KD * HID / 4);
  conv_split<<<dim3(KD * HID / 1024), blk, 0, stream>>>(W_k, wkh, wkl, KD * HID / 4);
  conv_split<<<dim3(VD * HID / 1024), blk, 0, stream>>>(W_v, wvh, wvl, VD * HID / 4);
  conv_split<<<dim3(VD * HID / 1024), blk, 0, stream>>>(W_g, wgh, wgl, VD * HID / 4);
  conv_split<<<dim3(HID * VD / 1024), blk, 0, stream>>>(W_o, woh, wol, HID * VD / 4);

  // xz = lerp(x, mu0) -> bf16 ; xp = tanh(xz @ W_x0^T)  [plain MFMA, padded N]
  lerp0_kernel<<<dim3(BT * HID / 1024), blk, 0, stream>>>(x, mu0, ah);
  gemm_mfma<1><<<dim3(2, 64), blk, 0, stream>>>(ah, wx0p, xp, R5, R5, HID);

  // slot 0 -> r  [split MFMA]
  gemm_bt<3, 2><<<dim3(8, 64), blk, 0, stream>>>(xp + 0 * RR, R5, W_x2 + 0 * RR, R5,
      ah, al, HID, BT, HID, RR, x_bias + 0 * HID, x);
  gemm_mfma3<<<dim3(4, 64), blk, 0, stream>>>(ah, al, wrh, wrl, rb, KD, KD, HID);
  // slot 1 -> w (fp32 path: tanh lora -> up + exp(-exp))
  gemm_bt<3, 0><<<dim3(8, 64), blk, 0, stream>>>(xp + 1 * RR, R5, W_x2 + 1 * RR, R5,
      buf, nullptr, HID, BT, HID, RR, x_bias + 1 * HID, x);
  gemm_bt<1, 0><<<dim3(1, 64), blk, 0, stream>>>(buf, HID, W_w1, HID, wlow, nullptr, GLR,
      BT, GLR, HID, nullptr, nullptr);
  gemm_bt<2, 0><<<dim3(4, 64), blk, 0, stream>>>(wlow, GLR, W_w2, GLR, db, nullptr, KD,
      BT, KD, GLR, b_w2, nullptr);
  // slot 2 -> k  [split MFMA]
  gemm_bt<3, 2><<<dim3(8, 64), blk, 0, stream>>>(xp + 2 * RR, R5, W_x2 + 2 * RR, R5,
      ah, al, HID, BT, HID, RR, x_bias + 2 * HID, x);
  gemm_mfma3<<<dim3(4, 64), blk, 0, stream>>>(ah, al, wkh, wkl, kb, KD, KD, HID);
  // slot 3 -> v  [split MFMA]
  gemm_bt<3, 2><<<dim3(8, 64), blk, 0, stream>>>(xp + 3 * RR, R5, W_x2 + 3 * RR, R5,
      ah, al, HID, BT, HID, RR, x_bias + 3 * HID, x);
  gemm_mfma3<<<dim3(8, 64), blk, 0, stream>>>(ah, al, wvh, wvl, vb, VD, VD, HID);
  // slot 4 -> g  [split MFMA]
  gemm_bt<3, 2><<<dim3(8, 64), blk, 0, stream>>>(xp + 4 * RR, R5, W_x2 + 4 * RR, R5,
      ah, al, HID, BT, HID, RR, x_bias + 4 * HID, x);
  gemm_mfma3<<<dim3(8, 64), blk, 0, stream>>>(ah, al, wgh, wgl, gb, VD, VD, HID);

  // bonus scalar, scan, groupnorm+gate (hi/lo), final projection [split MFMA]
  calc_c<<<dim3(BB * NH * TT / 4), blk, 0, stream>>>(rb, kb, bonus, cb);
  scan3_kernel<<<dim3(BB * NH * 32), blk, 0, stream>>>(rb, kb, db, vb, cb, ob);
  gn_gate<<<dim3(BT), blk, 0, stream>>>(ob, gb, gnw, gnb, ah, al);
  gemm_mfma3<<<dim3(8, 64), blk, 0, stream>>>(ah, al, woh, wol, out, HID, HID, HID);
}

// Round 8
// 1701.829 us; speedup vs baseline: 7.1951x; 1.0235x over previous
//
#include <hip/hip_runtime.h>
#include <hip/hip_bf16.h>

#define BB 4
#define TT 2048
#define HID 1024
#define NH 4
#define KD 512
#define VD 1024
#define DK 128
#define DV 256
#define RR 32
#define R5 160
#define GLR 64
#define BT (BB*TT)

typedef __attribute__((ext_vector_type(8))) short short8v;
typedef __attribute__((ext_vector_type(4))) float float4v;

__device__ __forceinline__ unsigned short f2bf(float f) {
  union { float f; unsigned u; } v; v.f = f;
  unsigned r = v.u + 0x7FFF + ((v.u >> 16) & 1);   // RNE
  return (unsigned short)(r >> 16);
}
__device__ __forceinline__ float bf2f(unsigned short h) {
  union { unsigned u; float f; } v; v.u = ((unsigned)h) << 16; return v.f;
}

__device__ __forceinline__ void gload_lds16(const unsigned short* g, unsigned short* l) {
  __builtin_amdgcn_global_load_lds(
      (const __attribute__((address_space(1))) unsigned int*)g,
      (__attribute__((address_space(3))) unsigned int*)l, 16, 0, 0);
}

// DPP-based add of a cross-lane source: x + dpp_ctrl(x). VALU pipe, no LDS.
template<int CTRL>
__device__ __forceinline__ float dpp_add(float x) {
  int xi = __builtin_bit_cast(int, x);
  int yi = __builtin_amdgcn_update_dpp(0, xi, CTRL, 0xf, 0xf, true);
  return x + __builtin_bit_cast(float, yi);
}

// ---------------- weight fp32 -> bf16 hi+lo split ----------------
__global__ __launch_bounds__(256) void conv_split(const float* __restrict__ src,
    unsigned short* __restrict__ hi, unsigned short* __restrict__ lo, int n4) {
  int i = blockIdx.x * 256 + threadIdx.x;
  if (i >= n4) return;
  float4 v = ((const float4*)src)[i];
  ushort4 h, l;
  h.x = f2bf(v.x); l.x = f2bf(v.x - bf2f(h.x));
  h.y = f2bf(v.y); l.y = f2bf(v.y - bf2f(h.y));
  h.z = f2bf(v.z); l.z = f2bf(v.z - bf2f(h.z));
  h.w = f2bf(v.w); l.w = f2bf(v.w - bf2f(h.w));
  ((ushort4*)hi)[i] = h; ((ushort4*)lo)[i] = l;
}

// W_x0 (160,1024) -> padded (256,1024) bf16 (hi only), zero rows >= 160
__global__ __launch_bounds__(256) void conv_bf16_pad(const float* __restrict__ src,
    unsigned short* __restrict__ dst) {
  int i = blockIdx.x * 256 + threadIdx.x;          // float4 index over 256*1024
  int row = i >> 8;
  ushort4 o; o.x = o.y = o.z = o.w = 0;
  if (row < R5) {
    float4 v = ((const float4*)src)[i];
    o.x = f2bf(v.x); o.y = f2bf(v.y); o.z = f2bf(v.z); o.w = f2bf(v.w);
  }
  ((ushort4*)dst)[i] = o;
}

// ---------------- elementwise: xz = x + (shift(x) - x) * mu0 -> bf16 ----------------
__global__ __launch_bounds__(256) void lerp0_kernel(const float* __restrict__ x,
    const float* __restrict__ mu0, unsigned short* __restrict__ out) {
  size_t i = (size_t)blockIdx.x * 256 + threadIdx.x;     // float4 index
  const int ncol4 = HID / 4;
  int c4 = (int)(i % ncol4);
  size_t tok = i / ncol4;
  int t = (int)(tok & (TT - 1));
  float4 xv = ((const float4*)x)[i];
  float4 m  = ((const float4*)mu0)[c4];
  float4 xs = make_float4(0.f, 0.f, 0.f, 0.f);
  if (t) xs = ((const float4*)x)[i - ncol4];
  ushort4 r;
  r.x = f2bf(xv.x + (xs.x - xv.x) * m.x);
  r.y = f2bf(xv.y + (xs.y - xv.y) * m.y);
  r.z = f2bf(xv.z + (xs.z - xv.z) * m.z);
  r.w = f2bf(xv.w + (xs.w - xv.w) * m.w);
  ((ushort4*)out)[i] = r;
}

// ---------------- plain bf16 MFMA GEMM (xp only): C = epi(A @ B^T), fp32 out ----------------
template<int EPI>
__global__ __launch_bounds__(256) void gemm_mfma(
    const unsigned short* __restrict__ A,
    const unsigned short* __restrict__ B,
    float* __restrict__ C, int ldc, int N, int K) {
  __shared__ unsigned short As[128 * 32];
  __shared__ unsigned short Bs[128 * 32];
  const int tid = threadIdx.x;
  const int l = tid & 63;
  const int w = tid >> 6;
  const int m0 = blockIdx.y * 128;
  const int n0 = blockIdx.x * 128;
  const int wr = (w >> 1) * 64;
  const int wc = (w & 1) * 64;

  float4v acc[4][4];
#pragma unroll
  for (int i = 0; i < 4; ++i)
#pragma unroll
    for (int j = 0; j < 4; ++j) acc[i][j] = (float4v){0.f, 0.f, 0.f, 0.f};

  const int c0 = w * 64 + l;
  const int c1 = 256 + c0;
  const unsigned short* gA0 = A + (size_t)(m0 + (c0 >> 2)) * K + (c0 & 3) * 8;
  const unsigned short* gA1 = A + (size_t)(m0 + (c1 >> 2)) * K + (c1 & 3) * 8;
  const unsigned short* gB0 = B + (size_t)(n0 + (c0 >> 2)) * K + (c0 & 3) * 8;
  const unsigned short* gB1 = B + (size_t)(n0 + (c1 >> 2)) * K + (c1 & 3) * 8;
  unsigned short* lA0 = &As[(w * 64) * 8];
  unsigned short* lA1 = &As[(256 + w * 64) * 8];
  unsigned short* lB0 = &Bs[(w * 64) * 8];
  unsigned short* lB1 = &Bs[(256 + w * 64) * 8];

  const int arow = (l & 15) * 32 + (l >> 4) * 8;

  for (int k0 = 0; k0 < K; k0 += 32) {
    gload_lds16(gA0, lA0);
    gload_lds16(gA1, lA1);
    gload_lds16(gB0, lB0);
    gload_lds16(gB1, lB1);
    gA0 += 32; gA1 += 32; gB0 += 32; gB1 += 32;
    __syncthreads();
    short8v a[4], b[4];
#pragma unroll
    for (int i = 0; i < 4; ++i)
      a[i] = *(const short8v*)&As[(wr + i * 16) * 32 + arow];
#pragma unroll
    for (int j = 0; j < 4; ++j)
      b[j] = *(const short8v*)&Bs[(wc + j * 16) * 32 + arow];
#pragma unroll
    for (int i = 0; i < 4; ++i)
#pragma unroll
      for (int j = 0; j < 4; ++j)
        acc[i][j] = __builtin_amdgcn_mfma_f32_16x16x32_bf16(a[i], b[j], acc[i][j], 0, 0, 0);
    __syncthreads();
  }

#pragma unroll
  for (int i = 0; i < 4; ++i) {
#pragma unroll
    for (int j = 0; j < 4; ++j) {
      int col = n0 + wc + j * 16 + (l & 15);
      if (col < N) {
#pragma unroll
        for (int q = 0; q < 4; ++q) {
          int row = m0 + wr + i * 16 + (l >> 4) * 4 + q;
          float v2 = acc[i][j][q];
          if (EPI == 1) v2 = tanhf(v2);
          C[(size_t)row * ldc + col] = v2;
        }
      }
    }
  }
}

// ---------------- split-bf16 3-pass MFMA GEMM: C = (Ah+Al) @ (Bh+Bl)^T, fp32 out ----
// Error ~2^-18 relative (fp32-class). A*: (M,K); B*: (N,K); C: (M,N).
__global__ __launch_bounds__(256) void gemm_mfma3(
    const unsigned short* __restrict__ Ah, const unsigned short* __restrict__ Al,
    const unsigned short* __restrict__ Bh, const unsigned short* __restrict__ Bl,
    float* __restrict__ C, int ldc, int N, int K) {
  __shared__ unsigned short AsH[128 * 32];
  __shared__ unsigned short AsL[128 * 32];
  __shared__ unsigned short BsH[128 * 32];
  __shared__ unsigned short BsL[128 * 32];
  const int tid = threadIdx.x;
  const int l = tid & 63;
  const int w = tid >> 6;
  const int m0 = blockIdx.y * 128;
  const int n0 = blockIdx.x * 128;
  const int wr = (w >> 1) * 64;
  const int wc = (w & 1) * 64;

  float4v acc[4][4];
#pragma unroll
  for (int i = 0; i < 4; ++i)
#pragma unroll
    for (int j = 0; j < 4; ++j) acc[i][j] = (float4v){0.f, 0.f, 0.f, 0.f};

  const int c0 = w * 64 + l;
  const int c1 = 256 + c0;
  const size_t oA0 = (size_t)(m0 + (c0 >> 2)) * K + (c0 & 3) * 8;
  const size_t oA1 = (size_t)(m0 + (c1 >> 2)) * K + (c1 & 3) * 8;
  const size_t oB0 = (size_t)(n0 + (c0 >> 2)) * K + (c0 & 3) * 8;
  const size_t oB1 = (size_t)(n0 + (c1 >> 2)) * K + (c1 & 3) * 8;
  const unsigned short* gAh0 = Ah + oA0; const unsigned short* gAh1 = Ah + oA1;
  const unsigned short* gAl0 = Al + oA0; const unsigned short* gAl1 = Al + oA1;
  const unsigned short* gBh0 = Bh + oB0; const unsigned short* gBh1 = Bh + oB1;
  const unsigned short* gBl0 = Bl + oB0; const unsigned short* gBl1 = Bl + oB1;
  unsigned short* lAh0 = &AsH[w * 512]; unsigned short* lAh1 = &AsH[2048 + w * 512];
  unsigned short* lAl0 = &AsL[w * 512]; unsigned short* lAl1 = &AsL[2048 + w * 512];
  unsigned short* lBh0 = &BsH[w * 512]; unsigned short* lBh1 = &BsH[2048 + w * 512];
  unsigned short* lBl0 = &BsL[w * 512]; unsigned short* lBl1 = &BsL[2048 + w * 512];

  const int arow = (l & 15) * 32 + (l >> 4) * 8;

  for (int k0 = 0; k0 < K; k0 += 32) {
    gload_lds16(gAh0, lAh0); gload_lds16(gAh1, lAh1);
    gload_lds16(gAl0, lAl0); gload_lds16(gAl1, lAl1);
    gload_lds16(gBh0, lBh0); gload_lds16(gBh1, lBh1);
    gload_lds16(gBl0, lBl0); gload_lds16(gBl1, lBl1);
    gAh0 += 32; gAh1 += 32; gAl0 += 32; gAl1 += 32;
    gBh0 += 32; gBh1 += 32; gBl0 += 32; gBl1 += 32;
    __syncthreads();
    short8v ah[4], al[4], bh[4], bl[4];
#pragma unroll
    for (int i = 0; i < 4; ++i) {
      ah[i] = *(const short8v*)&AsH[(wr + i * 16) * 32 + arow];
      al[i] = *(const short8v*)&AsL[(wr + i * 16) * 32 + arow];
    }
#pragma unroll
    for (int j = 0; j < 4; ++j) {
      bh[j] = *(const short8v*)&BsH[(wc + j * 16) * 32 + arow];
      bl[j] = *(const short8v*)&BsL[(wc + j * 16) * 32 + arow];
    }
#pragma unroll
    for (int i = 0; i < 4; ++i)
#pragma unroll
      for (int j = 0; j < 4; ++j) {
        acc[i][j] = __builtin_amdgcn_mfma_f32_16x16x32_bf16(ah[i], bh[j], acc[i][j], 0, 0, 0);
        acc[i][j] = __builtin_amdgcn_mfma_f32_16x16x32_bf16(al[i], bh[j], acc[i][j], 0, 0, 0);
        acc[i][j] = __builtin_amdgcn_mfma_f32_16x16x32_bf16(ah[i], bl[j], acc[i][j], 0, 0, 0);
      }
    __syncthreads();
  }

#pragma unroll
  for (int i = 0; i < 4; ++i) {
#pragma unroll
    for (int j = 0; j < 4; ++j) {
      int col = n0 + wc + j * 16 + (l & 15);
      if (col < N) {
#pragma unroll
        for (int q = 0; q < 4; ++q) {
          int row = m0 + wr + i * 16 + (l >> 4) * 4 + q;
          C[(size_t)row * ldc + col] = acc[i][j][q];
        }
      }
    }
  }
}

// ---------------- generic fp32 GEMM: C = epi(X @ W^T) ----------------
// EPI: 1 tanh | 2 exp(-exp(v + bias[n])) | 3 lerp: x + (shift-x)*(v+bias[n])
// OUT: 0 fp32 -> C0 ; 2 bf16 hi/lo pair -> C0,C1
template<int EPI, int OUT>
__global__ __launch_bounds__(256) void gemm_bt(
    const float* __restrict__ X, int lda,
    const float* __restrict__ W, int ldb,
    void* __restrict__ C0v, void* __restrict__ C1v, int ldc,
    int M, int N, int K,
    const float* __restrict__ bias,
    const float* __restrict__ ex) {
  __shared__ float As2[16][132];
  __shared__ float Bs2[16][132];
  const int tid = threadIdx.x;
  const int tx = tid & 15;
  const int ty = tid >> 4;
  const int m0 = blockIdx.y * 128;
  const int n0 = blockIdx.x * 128;
  float acc[8][8];
#pragma unroll
  for (int i = 0; i < 8; ++i)
#pragma unroll
    for (int j = 0; j < 8; ++j) acc[i][j] = 0.f;

  for (int k0 = 0; k0 < K; k0 += 16) {
#pragma unroll
    for (int s = 0; s < 2; ++s) {
      int q = s * 256 + tid;
      int row = q >> 2;
      int c4 = q & 3;
      float4 a = *(const float4*)&X[(size_t)(m0 + row) * lda + k0 + c4 * 4];
      As2[c4 * 4 + 0][row] = a.x; As2[c4 * 4 + 1][row] = a.y;
      As2[c4 * 4 + 2][row] = a.z; As2[c4 * 4 + 3][row] = a.w;
      int wr = n0 + row;
      float4 b = make_float4(0.f, 0.f, 0.f, 0.f);
      if (wr < N) b = *(const float4*)&W[(size_t)wr * ldb + k0 + c4 * 4];
      Bs2[c4 * 4 + 0][row] = b.x; Bs2[c4 * 4 + 1][row] = b.y;
      Bs2[c4 * 4 + 2][row] = b.z; Bs2[c4 * 4 + 3][row] = b.w;
    }
    __syncthreads();
#pragma unroll
    for (int kk = 0; kk < 16; ++kk) {
      float a[8], b[8];
#pragma unroll
      for (int p = 0; p < 4; ++p) {
        float2 t2 = *(const float2*)&As2[kk][ty * 8 + p * 2];
        a[p * 2] = t2.x; a[p * 2 + 1] = t2.y;
        float2 u2 = *(const float2*)&Bs2[kk][tx * 8 + p * 2];
        b[p * 2] = u2.x; b[p * 2 + 1] = u2.y;
      }
#pragma unroll
      for (int i = 0; i < 8; ++i)
#pragma unroll
        for (int j = 0; j < 8; ++j)
          acc[i][j] = fmaf(a[i], b[j], acc[i][j]);
    }
    __syncthreads();
  }
#pragma unroll
  for (int i = 0; i < 8; ++i) {
    int m = m0 + ty * 8 + i;
#pragma unroll
    for (int j = 0; j < 8; ++j) {
      int n = n0 + tx * 8 + j;
      if (n < N) {
        float v = acc[i][j];
        float res;
        if (EPI == 1) {
          res = tanhf(v);
        } else if (EPI == 2) {
          res = expf(-expf(v + bias[n]));
        } else {
          float xv = ex[(size_t)m * HID + n];
          int t = m & (TT - 1);
          float xs = t ? ex[(size_t)(m - 1) * HID + n] : 0.f;
          res = xv + (xs - xv) * (v + bias[n]);
        }
        size_t idx = (size_t)m * ldc + n;
        if (OUT == 0) {
          ((float*)C0v)[idx] = res;
        } else {
          unsigned short hv = f2bf(res);
          ((unsigned short*)C0v)[idx] = hv;
          ((unsigned short*)C1v)[idx] = f2bf(res - bf2f(hv));
        }
      }
    }
  }
}

// ---------------- c[b,h,t] = sum_dk r*u*k ----------------
__global__ __launch_bounds__(256) void calc_c(const float* __restrict__ r,
    const float* __restrict__ k, const float* __restrict__ u,
    float* __restrict__ c) {
  int idx = blockIdx.x * 4 + (threadIdx.x >> 6);   // (b*NH+h)*TT + t
  int lane = threadIdx.x & 63;
  int t = idx & (TT - 1);
  int bh = idx >> 11;
  int h = bh & (NH - 1);
  int b = bh >> 2;
  const float* rp = r + (size_t)(b * TT + t) * KD + h * DK;
  const float* kp = k + (size_t)(b * TT + t) * KD + h * DK;
  const float* up = u + h * DK;
  float2 rv = *(const float2*)&rp[lane * 2];
  float2 kv = *(const float2*)&kp[lane * 2];
  float2 uv = *(const float2*)&up[lane * 2];
  float p = rv.x * uv.x * kv.x + rv.y * uv.y * kv.y;
#pragma unroll
  for (int off = 32; off > 0; off >>= 1) p += __shfl_xor(p, off);
  if (lane == 0) c[idx] = p;
}

// ---------------- scan v4: 512 blocks (16 bh x 32 dv-chunks); thread = (dv, dk-slice of 4) ----
// dk-reduction via DPP (VALU pipe) instead of ds_swizzle: quad_perm xor1/xor2,
// half-mirror (xor4-equiv), mirror (xor8 -> row sums), row_bcast15 (cross-row).
// Result lands in lanes where (tid&31)==16.
__global__ __launch_bounds__(256) void scan4_kernel(
    const float* __restrict__ r, const float* __restrict__ k,
    const float* __restrict__ d, const float* __restrict__ v,
    const float* __restrict__ c, float* __restrict__ o) {
  const int bh = blockIdx.x >> 5;          // 0..15
  const int chunk = blockIdx.x & 31;       // dv chunk of 8
  const int b = bh >> 2, h = bh & (NH - 1);
  const int dkg = threadIdx.x & 31;        // dk group 0..31
  const int dvi = threadIdx.x >> 5;        // dv within chunk 0..7
  const int dv = chunk * 8 + dvi;

  const float* rp = r + (size_t)(b * TT) * KD + h * DK + dkg * 4;
  const float* kp = k + (size_t)(b * TT) * KD + h * DK + dkg * 4;
  const float* dp = d + (size_t)(b * TT) * KD + h * DK + dkg * 4;
  const float* vp = v + (size_t)(b * TT) * VD + h * DV + dv;
  const float* cp = c + (size_t)bh * TT;
  float* op = o + (size_t)(b * TT) * VD + h * DV + dv;

  float S0 = 0.f, S1 = 0.f, S2 = 0.f, S3 = 0.f;

  float4 rv = *(const float4*)rp;
  float4 kv = *(const float4*)kp;
  float4 dq = *(const float4*)dp;
  float vt = *vp;
  float ct = cp[0];

#pragma unroll 2
  for (int t = 0; t < TT; ++t) {
    float4 rn = *(const float4*)(rp + KD);
    float4 kn = *(const float4*)(kp + KD);
    float4 dn = *(const float4*)(dp + KD);
    float vn = vp[VD];
    float cn = cp[t + 1];

    float p = rv.x * S0;
    p = fmaf(rv.y, S1, p);
    p = fmaf(rv.z, S2, p);
    p = fmaf(rv.w, S3, p);

    S0 = fmaf(dq.x, S0, kv.x * vt);
    S1 = fmaf(dq.y, S1, kv.y * vt);
    S2 = fmaf(dq.z, S2, kv.z * vt);
    S3 = fmaf(dq.w, S3, kv.w * vt);

    // 32-lane reduce on the VALU pipe (DPP), ~5 dependent adds:
    p = dpp_add<0xB1>(p);    // quad_perm[1,0,3,2]  : + lane^1
    p = dpp_add<0x4E>(p);    // quad_perm[2,3,0,1]  : + lane^2
    p = dpp_add<0x141>(p);   // row_half_mirror     : + other quad (8-lane sums)
    p = dpp_add<0x140>(p);   // row_mirror          : + other 8 (16-lane row sums)
    p = dpp_add<0x142>(p);   // row_bcast15         : row0 sum -> row1 (lanes 16/48 = full sum)
    if (dkg == 16) *op = fmaf(ct, vt, p);

    rv = rn; kv = kn; dq = dn; vt = vn; ct = cn;
    rp += KD; kp += KD; dp += KD; vp += VD; op += VD;
  }
}

// ---------------- GroupNorm + affine + silu(g) gate -> bf16 hi/lo ----------------
__global__ __launch_bounds__(256) void gn_gate(const float* __restrict__ o,
    const float* __restrict__ g, const float* __restrict__ gnw,
    const float* __restrict__ gnb, unsigned short* __restrict__ ohi,
    unsigned short* __restrict__ olo) {
  int tok = blockIdx.x;
  int tid = threadIdx.x;
  __shared__ float s1[4], s2[4];
  for (int h = 0; h < NH; ++h) {
    int col = h * DV + tid;
    float val = o[(size_t)tok * VD + col];
    float a = val, bsq = val * val;
#pragma unroll
    for (int off = 32; off > 0; off >>= 1) {
      a += __shfl_xor(a, off);
      bsq += __shfl_xor(bsq, off);
    }
    int wid = tid >> 6;
    if ((tid & 63) == 0) { s1[wid] = a; s2[wid] = bsq; }
    __syncthreads();
    float S1 = s1[0] + s1[1] + s1[2] + s1[3];
    float S2 = s2[0] + s2[1] + s2[2] + s2[3];
    float mean = S1 * (1.f / DV);
    float var = S2 * (1.f / DV) - mean * mean;
    float xn = (val - mean) * rsqrtf(var + 1e-5f);
    float gv = g[(size_t)tok * VD + col];
    float sig = gv / (1.f + expf(-gv));
    float res = (xn * gnw[col] + gnb[col]) * sig;
    unsigned short hv = f2bf(res);
    ohi[(size_t)tok * VD + col] = hv;
    olo[(size_t)tok * VD + col] = f2bf(res - bf2f(hv));
    __syncthreads();
  }
}

extern "C" void kernel_launch(void* const* d_in, const int* in_sizes, int n_in,
                              void* d_out, int out_size, void* d_ws, size_t ws_size,
                              hipStream_t stream) {
  const float* x      = (const float*)d_in[0];
  const float* mu0    = (const float*)d_in[1];
  const float* W_x0   = (const float*)d_in[2];
  const float* W_x2   = (const float*)d_in[3];
  const float* x_bias = (const float*)d_in[4];
  const float* W_r    = (const float*)d_in[5];
  const float* W_w1   = (const float*)d_in[6];
  const float* W_w2   = (const float*)d_in[7];
  const float* b_w2   = (const float*)d_in[8];
  const float* W_k    = (const float*)d_in[9];
  const float* W_v    = (const float*)d_in[10];
  const float* W_g    = (const float*)d_in[11];
  const float* bonus  = (const float*)d_in[12];
  const float* gnw    = (const float*)d_in[13];
  const float* gnb    = (const float*)d_in[14];
  const float* W_o    = (const float*)d_in[15];
  float* out = (float*)d_out;

  float* ws = (float*)d_ws;
  size_t off = 0;
  float* buf  = ws + off; off += (size_t)BT * HID;   // fp32: w-lerp, then reused as scan output
  float* xp   = ws + off; off += (size_t)BT * R5;
  float* rb   = ws + off; off += (size_t)BT * KD;
  float* db   = ws + off; off += (size_t)BT * KD;
  float* kb   = ws + off; off += (size_t)BT * KD;
  float* vb   = ws + off; off += (size_t)BT * VD;
  float* gb   = ws + off; off += (size_t)BT * VD;
  float* wlow = ws + off; off += (size_t)BT * GLR;
  float* cb   = ws + off; off += (size_t)BB * NH * TT;
  float* ob   = buf;                                  // reuse (buf free after w-path)
  unsigned short* us = (unsigned short*)(ws + off);
  size_t uoff = 0;
  unsigned short* ah   = us + uoff; uoff += (size_t)BT * HID;  // bf16 A hi (reused)
  unsigned short* al   = us + uoff; uoff += (size_t)BT * HID;  // bf16 A lo (reused)
  unsigned short* wx0p = us + uoff; uoff += (size_t)256 * HID; // padded W_x0 (hi only)
  unsigned short* wrh  = us + uoff; uoff += (size_t)KD * HID;
  unsigned short* wrl  = us + uoff; uoff += (size_t)KD * HID;
  unsigned short* wkh  = us + uoff; uoff += (size_t)KD * HID;
  unsigned short* wkl  = us + uoff; uoff += (size_t)KD * HID;
  unsigned short* wvh  = us + uoff; uoff += (size_t)VD * HID;
  unsigned short* wvl  = us + uoff; uoff += (size_t)VD * HID;
  unsigned short* wgh  = us + uoff; uoff += (size_t)VD * HID;
  unsigned short* wgl  = us + uoff; uoff += (size_t)VD * HID;
  unsigned short* woh  = us + uoff; uoff += (size_t)HID * VD;
  unsigned short* wol  = us + uoff; uoff += (size_t)HID * VD;

  dim3 blk(256);

  // weight conversions
  conv_bf16_pad<<<dim3(256 * HID / 1024), blk, 0, stream>>>(W_x0, wx0p);
  conv_split<<<dim3(KD * HID / 1024), blk, 0, stream>>>(W_r, wrh, wrl, KD * HID / 4);
  conv_split<<<dim3(KD * HID / 1024), blk, 0, stream>>>(W_k, wkh, wkl, KD * HID / 4);
  conv_split<<<dim3(VD * HID / 1024), blk, 0, stream>>>(W_v, wvh, wvl, VD * HID / 4);
  conv_split<<<dim3(VD * HID / 1024), blk, 0, stream>>>(W_g, wgh, wgl, VD * HID / 4);
  conv_split<<<dim3(HID * VD / 1024), blk, 0, stream>>>(W_o, woh, wol, HID * VD / 4);

  // xz = lerp(x, mu0) -> bf16 ; xp = tanh(xz @ W_x0^T)  [plain MFMA, padded N]
  lerp0_kernel<<<dim3(BT * HID / 1024), blk, 0, stream>>>(x, mu0, ah);
  gemm_mfma<1><<<dim3(2, 64), blk, 0, stream>>>(ah, wx0p, xp, R5, R5, HID);

  // slot 0 -> r  [split MFMA]
  gemm_bt<3, 2><<<dim3(8, 64), blk, 0, stream>>>(xp + 0 * RR, R5, W_x2 + 0 * RR, R5,
      ah, al, HID, BT, HID, RR, x_bias + 0 * HID, x);
  gemm_mfma3<<<dim3(4, 64), blk, 0, stream>>>(ah, al, wrh, wrl, rb, KD, KD, HID);
  // slot 1 -> w (fp32 path: tanh lora -> up + exp(-exp))
  gemm_bt<3, 0><<<dim3(8, 64), blk, 0, stream>>>(xp + 1 * RR, R5, W_x2 + 1 * RR, R5,
      buf, nullptr, HID, BT, HID, RR, x_bias + 1 * HID, x);
  gemm_bt<1, 0><<<dim3(1, 64), blk, 0, stream>>>(buf, HID, W_w1, HID, wlow, nullptr, GLR,
      BT, GLR, HID, nullptr, nullptr);
  gemm_bt<2, 0><<<dim3(4, 64), blk, 0, stream>>>(wlow, GLR, W_w2, GLR, db, nullptr, KD,
      BT, KD, GLR, b_w2, nullptr);
  // slot 2 -> k  [split MFMA]
  gemm_bt<3, 2><<<dim3(8, 64), blk, 0, stream>>>(xp + 2 * RR, R5, W_x2 + 2 * RR, R5,
      ah, al, HID, BT, HID, RR, x_bias + 2 * HID, x);
  gemm_mfma3<<<dim3(4, 64), blk, 0, stream>>>(ah, al, wkh, wkl, kb, KD, KD, HID);
  // slot 3 -> v  [split MFMA]
  gemm_bt<3, 2><<<dim3(8, 64), blk, 0, stream>>>(xp + 3 * RR, R5, W_x2 + 3 * RR, R5,
      ah, al, HID, BT, HID, RR, x_bias + 3 * HID, x);
  gemm_mfma3<<<dim3(8, 64), blk, 0, stream>>>(ah, al, wvh, wvl, vb, VD, VD, HID);
  // slot 4 -> g  [split MFMA]
  gemm_bt<3, 2><<<dim3(8, 64), blk, 0, stream>>>(xp + 4 * RR, R5, W_x2 + 4 * RR, R5,
      ah, al, HID, BT, HID, RR, x_bias + 4 * HID, x);
  gemm_mfma3<<<dim3(8, 64), blk, 0, stream>>>(ah, al, wgh, wgl, gb, VD, VD, HID);

  // bonus scalar, scan (DPP reduce), groupnorm+gate (hi/lo), final projection [split MFMA]
  calc_c<<<dim3(BB * NH * TT / 4), blk, 0, stream>>>(rb, kb, bonus, cb);
  scan4_kernel<<<dim3(BB * NH * 32), blk, 0, stream>>>(rb, kb, db, vb, cb, ob);
  gn_gate<<<dim3(BT), blk, 0, stream>>>(ob, gb, gnw, gnb, ah, al);
  gemm_mfma3<<<dim3(8, 64), blk, 0, stream>>>(ah, al, woh, wol, out, HID, HID, HID);
}

// Round 9
// 1446.835 us; speedup vs baseline: 8.4632x; 1.1762x over previous
//
#include <hip/hip_runtime.h>
#include <hip/hip_bf16.h>

#define BB 4
#define TT 2048
#define HID 1024
#define NH 4
#define KD 512
#define VD 1024
#define DK 128
#define DV 256
#define RR 32
#define R5 160
#define GLR 64
#define BT (BB*TT)
#define PD 8

typedef __attribute__((ext_vector_type(8))) short short8v;
typedef __attribute__((ext_vector_type(4))) float float4v;

__device__ __forceinline__ unsigned short f2bf(float f) {
  union { float f; unsigned u; } v; v.f = f;
  unsigned r = v.u + 0x7FFF + ((v.u >> 16) & 1);   // RNE
  return (unsigned short)(r >> 16);
}
__device__ __forceinline__ float bf2f(unsigned short h) {
  union { unsigned u; float f; } v; v.u = ((unsigned)h) << 16; return v.f;
}

__device__ __forceinline__ void gload_lds16(const unsigned short* g, unsigned short* l) {
  __builtin_amdgcn_global_load_lds(
      (const __attribute__((address_space(1))) unsigned int*)g,
      (__attribute__((address_space(3))) unsigned int*)l, 16, 0, 0);
}

// DPP-based add of a cross-lane source: x + dpp_ctrl(x). VALU pipe, no LDS.
template<int CTRL>
__device__ __forceinline__ float dpp_add(float x) {
  int xi = __builtin_bit_cast(int, x);
  int yi = __builtin_amdgcn_update_dpp(0, xi, CTRL, 0xf, 0xf, true);
  return x + __builtin_bit_cast(float, yi);
}

// ---------------- weight fp32 -> bf16 hi+lo split ----------------
__global__ __launch_bounds__(256) void conv_split(const float* __restrict__ src,
    unsigned short* __restrict__ hi, unsigned short* __restrict__ lo, int n4) {
  int i = blockIdx.x * 256 + threadIdx.x;
  if (i >= n4) return;
  float4 v = ((const float4*)src)[i];
  ushort4 h, l;
  h.x = f2bf(v.x); l.x = f2bf(v.x - bf2f(h.x));
  h.y = f2bf(v.y); l.y = f2bf(v.y - bf2f(h.y));
  h.z = f2bf(v.z); l.z = f2bf(v.z - bf2f(h.z));
  h.w = f2bf(v.w); l.w = f2bf(v.w - bf2f(h.w));
  ((ushort4*)hi)[i] = h; ((ushort4*)lo)[i] = l;
}

// W_x0 (160,1024) -> padded (256,1024) bf16 (hi only), zero rows >= 160
__global__ __launch_bounds__(256) void conv_bf16_pad(const float* __restrict__ src,
    unsigned short* __restrict__ dst) {
  int i = blockIdx.x * 256 + threadIdx.x;          // float4 index over 256*1024
  int row = i >> 8;
  ushort4 o; o.x = o.y = o.z = o.w = 0;
  if (row < R5) {
    float4 v = ((const float4*)src)[i];
    o.x = f2bf(v.x); o.y = f2bf(v.y); o.z = f2bf(v.z); o.w = f2bf(v.w);
  }
  ((ushort4*)dst)[i] = o;
}

// ---------------- elementwise: xz = x + (shift(x) - x) * mu0 -> bf16 ----------------
__global__ __launch_bounds__(256) void lerp0_kernel(const float* __restrict__ x,
    const float* __restrict__ mu0, unsigned short* __restrict__ out) {
  size_t i = (size_t)blockIdx.x * 256 + threadIdx.x;     // float4 index
  const int ncol4 = HID / 4;
  int c4 = (int)(i % ncol4);
  size_t tok = i / ncol4;
  int t = (int)(tok & (TT - 1));
  float4 xv = ((const float4*)x)[i];
  float4 m  = ((const float4*)mu0)[c4];
  float4 xs = make_float4(0.f, 0.f, 0.f, 0.f);
  if (t) xs = ((const float4*)x)[i - ncol4];
  ushort4 r;
  r.x = f2bf(xv.x + (xs.x - xv.x) * m.x);
  r.y = f2bf(xv.y + (xs.y - xv.y) * m.y);
  r.z = f2bf(xv.z + (xs.z - xv.z) * m.z);
  r.w = f2bf(xv.w + (xs.w - xv.w) * m.w);
  ((ushort4*)out)[i] = r;
}

// ---------------- plain bf16 MFMA GEMM (xp only): C = epi(A @ B^T), fp32 out ----------------
template<int EPI>
__global__ __launch_bounds__(256) void gemm_mfma(
    const unsigned short* __restrict__ A,
    const unsigned short* __restrict__ B,
    float* __restrict__ C, int ldc, int N, int K) {
  __shared__ unsigned short As[128 * 32];
  __shared__ unsigned short Bs[128 * 32];
  const int tid = threadIdx.x;
  const int l = tid & 63;
  const int w = tid >> 6;
  const int m0 = blockIdx.y * 128;
  const int n0 = blockIdx.x * 128;
  const int wr = (w >> 1) * 64;
  const int wc = (w & 1) * 64;

  float4v acc[4][4];
#pragma unroll
  for (int i = 0; i < 4; ++i)
#pragma unroll
    for (int j = 0; j < 4; ++j) acc[i][j] = (float4v){0.f, 0.f, 0.f, 0.f};

  const int c0 = w * 64 + l;
  const int c1 = 256 + c0;
  const unsigned short* gA0 = A + (size_t)(m0 + (c0 >> 2)) * K + (c0 & 3) * 8;
  const unsigned short* gA1 = A + (size_t)(m0 + (c1 >> 2)) * K + (c1 & 3) * 8;
  const unsigned short* gB0 = B + (size_t)(n0 + (c0 >> 2)) * K + (c0 & 3) * 8;
  const unsigned short* gB1 = B + (size_t)(n0 + (c1 >> 2)) * K + (c1 & 3) * 8;
  unsigned short* lA0 = &As[(w * 64) * 8];
  unsigned short* lA1 = &As[(256 + w * 64) * 8];
  unsigned short* lB0 = &Bs[(w * 64) * 8];
  unsigned short* lB1 = &Bs[(256 + w * 64) * 8];

  const int arow = (l & 15) * 32 + (l >> 4) * 8;

  for (int k0 = 0; k0 < K; k0 += 32) {
    gload_lds16(gA0, lA0);
    gload_lds16(gA1, lA1);
    gload_lds16(gB0, lB0);
    gload_lds16(gB1, lB1);
    gA0 += 32; gA1 += 32; gB0 += 32; gB1 += 32;
    __syncthreads();
    short8v a[4], b[4];
#pragma unroll
    for (int i = 0; i < 4; ++i)
      a[i] = *(const short8v*)&As[(wr + i * 16) * 32 + arow];
#pragma unroll
    for (int j = 0; j < 4; ++j)
      b[j] = *(const short8v*)&Bs[(wc + j * 16) * 32 + arow];
#pragma unroll
    for (int i = 0; i < 4; ++i)
#pragma unroll
      for (int j = 0; j < 4; ++j)
        acc[i][j] = __builtin_amdgcn_mfma_f32_16x16x32_bf16(a[i], b[j], acc[i][j], 0, 0, 0);
    __syncthreads();
  }

#pragma unroll
  for (int i = 0; i < 4; ++i) {
#pragma unroll
    for (int j = 0; j < 4; ++j) {
      int col = n0 + wc + j * 16 + (l & 15);
      if (col < N) {
#pragma unroll
        for (int q = 0; q < 4; ++q) {
          int row = m0 + wr + i * 16 + (l >> 4) * 4 + q;
          float v2 = acc[i][j][q];
          if (EPI == 1) v2 = tanhf(v2);
          C[(size_t)row * ldc + col] = v2;
        }
      }
    }
  }
}

// ---------------- split-bf16 3-pass MFMA GEMM: C = (Ah+Al) @ (Bh+Bl)^T, fp32 out ----
// Error ~2^-18 relative (fp32-class). A*: (M,K); B*: (N,K); C: (M,N).
__global__ __launch_bounds__(256) void gemm_mfma3(
    const unsigned short* __restrict__ Ah, const unsigned short* __restrict__ Al,
    const unsigned short* __restrict__ Bh, const unsigned short* __restrict__ Bl,
    float* __restrict__ C, int ldc, int N, int K) {
  __shared__ unsigned short AsH[128 * 32];
  __shared__ unsigned short AsL[128 * 32];
  __shared__ unsigned short BsH[128 * 32];
  __shared__ unsigned short BsL[128 * 32];
  const int tid = threadIdx.x;
  const int l = tid & 63;
  const int w = tid >> 6;
  const int m0 = blockIdx.y * 128;
  const int n0 = blockIdx.x * 128;
  const int wr = (w >> 1) * 64;
  const int wc = (w & 1) * 64;

  float4v acc[4][4];
#pragma unroll
  for (int i = 0; i < 4; ++i)
#pragma unroll
    for (int j = 0; j < 4; ++j) acc[i][j] = (float4v){0.f, 0.f, 0.f, 0.f};

  const int c0 = w * 64 + l;
  const int c1 = 256 + c0;
  const size_t oA0 = (size_t)(m0 + (c0 >> 2)) * K + (c0 & 3) * 8;
  const size_t oA1 = (size_t)(m0 + (c1 >> 2)) * K + (c1 & 3) * 8;
  const size_t oB0 = (size_t)(n0 + (c0 >> 2)) * K + (c0 & 3) * 8;
  const size_t oB1 = (size_t)(n0 + (c1 >> 2)) * K + (c1 & 3) * 8;
  const unsigned short* gAh0 = Ah + oA0; const unsigned short* gAh1 = Ah + oA1;
  const unsigned short* gAl0 = Al + oA0; const unsigned short* gAl1 = Al + oA1;
  const unsigned short* gBh0 = Bh + oB0; const unsigned short* gBh1 = Bh + oB1;
  const unsigned short* gBl0 = Bl + oB0; const unsigned short* gBl1 = Bl + oB1;
  unsigned short* lAh0 = &AsH[w * 512]; unsigned short* lAh1 = &AsH[2048 + w * 512];
  unsigned short* lAl0 = &AsL[w * 512]; unsigned short* lAl1 = &AsL[2048 + w * 512];
  unsigned short* lBh0 = &BsH[w * 512]; unsigned short* lBh1 = &BsH[2048 + w * 512];
  unsigned short* lBl0 = &BsL[w * 512]; unsigned short* lBl1 = &BsL[2048 + w * 512];

  const int arow = (l & 15) * 32 + (l >> 4) * 8;

  for (int k0 = 0; k0 < K; k0 += 32) {
    gload_lds16(gAh0, lAh0); gload_lds16(gAh1, lAh1);
    gload_lds16(gAl0, lAl0); gload_lds16(gAl1, lAl1);
    gload_lds16(gBh0, lBh0); gload_lds16(gBh1, lBh1);
    gload_lds16(gBl0, lBl0); gload_lds16(gBl1, lBl1);
    gAh0 += 32; gAh1 += 32; gAl0 += 32; gAl1 += 32;
    gBh0 += 32; gBh1 += 32; gBl0 += 32; gBl1 += 32;
    __syncthreads();
    short8v ah[4], al[4], bh[4], bl[4];
#pragma unroll
    for (int i = 0; i < 4; ++i) {
      ah[i] = *(const short8v*)&AsH[(wr + i * 16) * 32 + arow];
      al[i] = *(const short8v*)&AsL[(wr + i * 16) * 32 + arow];
    }
#pragma unroll
    for (int j = 0; j < 4; ++j) {
      bh[j] = *(const short8v*)&BsH[(wc + j * 16) * 32 + arow];
      bl[j] = *(const short8v*)&BsL[(wc + j * 16) * 32 + arow];
    }
#pragma unroll
    for (int i = 0; i < 4; ++i)
#pragma unroll
      for (int j = 0; j < 4; ++j) {
        acc[i][j] = __builtin_amdgcn_mfma_f32_16x16x32_bf16(ah[i], bh[j], acc[i][j], 0, 0, 0);
        acc[i][j] = __builtin_amdgcn_mfma_f32_16x16x32_bf16(al[i], bh[j], acc[i][j], 0, 0, 0);
        acc[i][j] = __builtin_amdgcn_mfma_f32_16x16x32_bf16(ah[i], bl[j], acc[i][j], 0, 0, 0);
      }
    __syncthreads();
  }

#pragma unroll
  for (int i = 0; i < 4; ++i) {
#pragma unroll
    for (int j = 0; j < 4; ++j) {
      int col = n0 + wc + j * 16 + (l & 15);
      if (col < N) {
#pragma unroll
        for (int q = 0; q < 4; ++q) {
          int row = m0 + wr + i * 16 + (l >> 4) * 4 + q;
          C[(size_t)row * ldc + col] = acc[i][j][q];
        }
      }
    }
  }
}

// ---------------- generic fp32 GEMM: C = epi(X @ W^T) ----------------
// EPI: 1 tanh | 2 exp(-exp(v + bias[n])) | 3 lerp: x + (shift-x)*(v+bias[n])
// OUT: 0 fp32 -> C0 ; 2 bf16 hi/lo pair -> C0,C1
template<int EPI, int OUT>
__global__ __launch_bounds__(256) void gemm_bt(
    const float* __restrict__ X, int lda,
    const float* __restrict__ W, int ldb,
    void* __restrict__ C0v, void* __restrict__ C1v, int ldc,
    int M, int N, int K,
    const float* __restrict__ bias,
    const float* __restrict__ ex) {
  __shared__ float As2[16][132];
  __shared__ float Bs2[16][132];
  const int tid = threadIdx.x;
  const int tx = tid & 15;
  const int ty = tid >> 4;
  const int m0 = blockIdx.y * 128;
  const int n0 = blockIdx.x * 128;
  float acc[8][8];
#pragma unroll
  for (int i = 0; i < 8; ++i)
#pragma unroll
    for (int j = 0; j < 8; ++j) acc[i][j] = 0.f;

  for (int k0 = 0; k0 < K; k0 += 16) {
#pragma unroll
    for (int s = 0; s < 2; ++s) {
      int q = s * 256 + tid;
      int row = q >> 2;
      int c4 = q & 3;
      float4 a = *(const float4*)&X[(size_t)(m0 + row) * lda + k0 + c4 * 4];
      As2[c4 * 4 + 0][row] = a.x; As2[c4 * 4 + 1][row] = a.y;
      As2[c4 * 4 + 2][row] = a.z; As2[c4 * 4 + 3][row] = a.w;
      int wr = n0 + row;
      float4 b = make_float4(0.f, 0.f, 0.f, 0.f);
      if (wr < N) b = *(const float4*)&W[(size_t)wr * ldb + k0 + c4 * 4];
      Bs2[c4 * 4 + 0][row] = b.x; Bs2[c4 * 4 + 1][row] = b.y;
      Bs2[c4 * 4 + 2][row] = b.z; Bs2[c4 * 4 + 3][row] = b.w;
    }
    __syncthreads();
#pragma unroll
    for (int kk = 0; kk < 16; ++kk) {
      float a[8], b[8];
#pragma unroll
      for (int p = 0; p < 4; ++p) {
        float2 t2 = *(const float2*)&As2[kk][ty * 8 + p * 2];
        a[p * 2] = t2.x; a[p * 2 + 1] = t2.y;
        float2 u2 = *(const float2*)&Bs2[kk][tx * 8 + p * 2];
        b[p * 2] = u2.x; b[p * 2 + 1] = u2.y;
      }
#pragma unroll
      for (int i = 0; i < 8; ++i)
#pragma unroll
        for (int j = 0; j < 8; ++j)
          acc[i][j] = fmaf(a[i], b[j], acc[i][j]);
    }
    __syncthreads();
  }
#pragma unroll
  for (int i = 0; i < 8; ++i) {
    int m = m0 + ty * 8 + i;
#pragma unroll
    for (int j = 0; j < 8; ++j) {
      int n = n0 + tx * 8 + j;
      if (n < N) {
        float v = acc[i][j];
        float res;
        if (EPI == 1) {
          res = tanhf(v);
        } else if (EPI == 2) {
          res = expf(-expf(v + bias[n]));
        } else {
          float xv = ex[(size_t)m * HID + n];
          int t = m & (TT - 1);
          float xs = t ? ex[(size_t)(m - 1) * HID + n] : 0.f;
          res = xv + (xs - xv) * (v + bias[n]);
        }
        size_t idx = (size_t)m * ldc + n;
        if (OUT == 0) {
          ((float*)C0v)[idx] = res;
        } else {
          unsigned short hv = f2bf(res);
          ((unsigned short*)C0v)[idx] = hv;
          ((unsigned short*)C1v)[idx] = f2bf(res - bf2f(hv));
        }
      }
    }
  }
}

// ---------------- c[b,h,t] = sum_dk r*u*k ----------------
__global__ __launch_bounds__(256) void calc_c(const float* __restrict__ r,
    const float* __restrict__ k, const float* __restrict__ u,
    float* __restrict__ c) {
  int idx = blockIdx.x * 4 + (threadIdx.x >> 6);   // (b*NH+h)*TT + t
  int lane = threadIdx.x & 63;
  int t = idx & (TT - 1);
  int bh = idx >> 11;
  int h = bh & (NH - 1);
  int b = bh >> 2;
  const float* rp = r + (size_t)(b * TT + t) * KD + h * DK;
  const float* kp = k + (size_t)(b * TT + t) * KD + h * DK;
  const float* up = u + h * DK;
  float2 rv = *(const float2*)&rp[lane * 2];
  float2 kv = *(const float2*)&kp[lane * 2];
  float2 uv = *(const float2*)&up[lane * 2];
  float p = rv.x * uv.x * kv.x + rv.y * uv.y * kv.y;
#pragma unroll
  for (int off = 32; off > 0; off >>= 1) p += __shfl_xor(p, off);
  if (lane == 0) c[idx] = p;
}

// ---------------- scan v5: depth-8 modulo-scheduled register pipeline ----------------
// 512 blocks (16 bh x 32 dv-chunks); thread = (dv, dk-slice of 4). Each phase
// consumes slot p then re-issues its loads for step t+p+PD: ~48 outstanding
// loads/wave hide HBM latency. DPP reduce (VALU pipe) as validated in R8.
// Tail prefetch over-reads <= PD rows into the adjacent ws buffer (safe).
__global__ __launch_bounds__(256) void scan5_kernel(
    const float* __restrict__ r, const float* __restrict__ k,
    const float* __restrict__ d, const float* __restrict__ v,
    const float* __restrict__ c, float* __restrict__ o) {
  const int bh = blockIdx.x >> 5;          // 0..15
  const int chunk = blockIdx.x & 31;       // dv chunk of 8
  const int b = bh >> 2, h = bh & (NH - 1);
  const int dkg = threadIdx.x & 31;        // dk group 0..31
  const int dvi = threadIdx.x >> 5;        // dv within chunk 0..7
  const int dv = chunk * 8 + dvi;

  const float* rp = r + (size_t)(b * TT) * KD + h * DK + dkg * 4;
  const float* kp = k + (size_t)(b * TT) * KD + h * DK + dkg * 4;
  const float* dp = d + (size_t)(b * TT) * KD + h * DK + dkg * 4;
  const float* vp = v + (size_t)(b * TT) * VD + h * DV + dv;
  const float* cp = c + (size_t)bh * TT;
  float* op = o + (size_t)(b * TT) * VD + h * DV + dv;

  float S0 = 0.f, S1 = 0.f, S2 = 0.f, S3 = 0.f;

  float4 rv[PD], kv[PD], dq[PD];
  float vt[PD], ct[PD];
#pragma unroll
  for (int p = 0; p < PD; ++p) {
    rv[p] = *(const float4*)(rp + (size_t)p * KD);
    kv[p] = *(const float4*)(kp + (size_t)p * KD);
    dq[p] = *(const float4*)(dp + (size_t)p * KD);
    vt[p] = vp[(size_t)p * VD];
    ct[p] = cp[p];
  }

  for (int t = 0; t < TT; t += PD) {
#pragma unroll
    for (int p = 0; p < PD; ++p) {
      // consume slot p (logical step t+p)
      float pz = rv[p].x * S0;
      pz = fmaf(rv[p].y, S1, pz);
      pz = fmaf(rv[p].z, S2, pz);
      pz = fmaf(rv[p].w, S3, pz);

      S0 = fmaf(dq[p].x, S0, kv[p].x * vt[p]);
      S1 = fmaf(dq[p].y, S1, kv[p].y * vt[p]);
      S2 = fmaf(dq[p].z, S2, kv[p].z * vt[p]);
      S3 = fmaf(dq[p].w, S3, kv[p].w * vt[p]);

      float cct = ct[p], vvt = vt[p];   // keep before slot refill

      // refill slot p with logical step t+p+PD
      rv[p] = *(const float4*)(rp + (size_t)(p + PD) * KD);
      kv[p] = *(const float4*)(kp + (size_t)(p + PD) * KD);
      dq[p] = *(const float4*)(dp + (size_t)(p + PD) * KD);
      vt[p] = vp[(size_t)(p + PD) * VD];
      ct[p] = cp[t + p + PD];

      // 32-lane reduce on the VALU pipe (DPP):
      pz = dpp_add<0xB1>(pz);    // + lane^1
      pz = dpp_add<0x4E>(pz);    // + lane^2
      pz = dpp_add<0x141>(pz);   // row_half_mirror (8-lane sums)
      pz = dpp_add<0x140>(pz);   // row_mirror (16-lane row sums)
      pz = dpp_add<0x142>(pz);   // row_bcast15 (lane 16/48 = 32-lane sum)
      if (dkg == 16) op[(size_t)p * VD] = fmaf(cct, vvt, pz);
    }
    rp += PD * KD; kp += PD * KD; dp += PD * KD; vp += PD * VD; op += PD * VD;
  }
}

// ---------------- GroupNorm + affine + silu(g) gate -> bf16 hi/lo ----------------
__global__ __launch_bounds__(256) void gn_gate(const float* __restrict__ o,
    const float* __restrict__ g, const float* __restrict__ gnw,
    const float* __restrict__ gnb, unsigned short* __restrict__ ohi,
    unsigned short* __restrict__ olo) {
  int tok = blockIdx.x;
  int tid = threadIdx.x;
  __shared__ float s1[4], s2[4];
  for (int h = 0; h < NH; ++h) {
    int col = h * DV + tid;
    float val = o[(size_t)tok * VD + col];
    float a = val, bsq = val * val;
#pragma unroll
    for (int off = 32; off > 0; off >>= 1) {
      a += __shfl_xor(a, off);
      bsq += __shfl_xor(bsq, off);
    }
    int wid = tid >> 6;
    if ((tid & 63) == 0) { s1[wid] = a; s2[wid] = bsq; }
    __syncthreads();
    float S1 = s1[0] + s1[1] + s1[2] + s1[3];
    float S2 = s2[0] + s2[1] + s2[2] + s2[3];
    float mean = S1 * (1.f / DV);
    float var = S2 * (1.f / DV) - mean * mean;
    float xn = (val - mean) * rsqrtf(var + 1e-5f);
    float gv = g[(size_t)tok * VD + col];
    float sig = gv / (1.f + expf(-gv));
    float res = (xn * gnw[col] + gnb[col]) * sig;
    unsigned short hv = f2bf(res);
    ohi[(size_t)tok * VD + col] = hv;
    olo[(size_t)tok * VD + col] = f2bf(res - bf2f(hv));
    __syncthreads();
  }
}

extern "C" void kernel_launch(void* const* d_in, const int* in_sizes, int n_in,
                              void* d_out, int out_size, void* d_ws, size_t ws_size,
                              hipStream_t stream) {
  const float* x      = (const float*)d_in[0];
  const float* mu0    = (const float*)d_in[1];
  const float* W_x0   = (const float*)d_in[2];
  const float* W_x2   = (const float*)d_in[3];
  const float* x_bias = (const float*)d_in[4];
  const float* W_r    = (const float*)d_in[5];
  const float* W_w1   = (const float*)d_in[6];
  const float* W_w2   = (const float*)d_in[7];
  const float* b_w2   = (const float*)d_in[8];
  const float* W_k    = (const float*)d_in[9];
  const float* W_v    = (const float*)d_in[10];
  const float* W_g    = (const float*)d_in[11];
  const float* bonus  = (const float*)d_in[12];
  const float* gnw    = (const float*)d_in[13];
  const float* gnb    = (const float*)d_in[14];
  const float* W_o    = (const float*)d_in[15];
  float* out = (float*)d_out;

  float* ws = (float*)d_ws;
  size_t off = 0;
  float* buf  = ws + off; off += (size_t)BT * HID;   // fp32: w-lerp, then reused as scan output
  float* xp   = ws + off; off += (size_t)BT * R5;
  float* rb   = ws + off; off += (size_t)BT * KD;
  float* db   = ws + off; off += (size_t)BT * KD;
  float* kb   = ws + off; off += (size_t)BT * KD;
  float* vb   = ws + off; off += (size_t)BT * VD;
  float* gb   = ws + off; off += (size_t)BT * VD;
  float* wlow = ws + off; off += (size_t)BT * GLR;
  float* cb   = ws + off; off += (size_t)BB * NH * TT;
  float* ob   = buf;                                  // reuse (buf free after w-path)
  unsigned short* us = (unsigned short*)(ws + off);
  size_t uoff = 0;
  unsigned short* ah   = us + uoff; uoff += (size_t)BT * HID;  // bf16 A hi (reused)
  unsigned short* al   = us + uoff; uoff += (size_t)BT * HID;  // bf16 A lo (reused)
  unsigned short* wx0p = us + uoff; uoff += (size_t)256 * HID; // padded W_x0 (hi only)
  unsigned short* wrh  = us + uoff; uoff += (size_t)KD * HID;
  unsigned short* wrl  = us + uoff; uoff += (size_t)KD * HID;
  unsigned short* wkh  = us + uoff; uoff += (size_t)KD * HID;
  unsigned short* wkl  = us + uoff; uoff += (size_t)KD * HID;
  unsigned short* wvh  = us + uoff; uoff += (size_t)VD * HID;
  unsigned short* wvl  = us + uoff; uoff += (size_t)VD * HID;
  unsigned short* wgh  = us + uoff; uoff += (size_t)VD * HID;
  unsigned short* wgl  = us + uoff; uoff += (size_t)VD * HID;
  unsigned short* woh  = us + uoff; uoff += (size_t)HID * VD;
  unsigned short* wol  = us + uoff; uoff += (size_t)HID * VD;

  dim3 blk(256);

  // weight conversions
  conv_bf16_pad<<<dim3(256 * HID / 1024), blk, 0, stream>>>(W_x0, wx0p);
  conv_split<<<dim3(KD * HID / 1024), blk, 0, stream>>>(W_r, wrh, wrl, KD * HID / 4);
  conv_split<<<dim3(KD * HID / 1024), blk, 0, stream>>>(W_k, wkh, wkl, KD * HID / 4);
  conv_split<<<dim3(VD * HID / 1024), blk, 0, stream>>>(W_v, wvh, wvl, VD * HID / 4);
  conv_split<<<dim3(VD * HID / 1024), blk, 0, stream>>>(W_g, wgh, wgl, VD * HID / 4);
  conv_split<<<dim3(HID * VD / 1024), blk, 0, stream>>>(W_o, woh, wol, HID * VD / 4);

  // xz = lerp(x, mu0) -> bf16 ; xp = tanh(xz @ W_x0^T)  [plain MFMA, padded N]
  lerp0_kernel<<<dim3(BT * HID / 1024), blk, 0, stream>>>(x, mu0, ah);
  gemm_mfma<1><<<dim3(2, 64), blk, 0, stream>>>(ah, wx0p, xp, R5, R5, HID);

  // slot 0 -> r  [split MFMA]
  gemm_bt<3, 2><<<dim3(8, 64), blk, 0, stream>>>(xp + 0 * RR, R5, W_x2 + 0 * RR, R5,
      ah, al, HID, BT, HID, RR, x_bias + 0 * HID, x);
  gemm_mfma3<<<dim3(4, 64), blk, 0, stream>>>(ah, al, wrh, wrl, rb, KD, KD, HID);
  // slot 1 -> w (fp32 path: tanh lora -> up + exp(-exp))
  gemm_bt<3, 0><<<dim3(8, 64), blk, 0, stream>>>(xp + 1 * RR, R5, W_x2 + 1 * RR, R5,
      buf, nullptr, HID, BT, HID, RR, x_bias + 1 * HID, x);
  gemm_bt<1, 0><<<dim3(1, 64), blk, 0, stream>>>(buf, HID, W_w1, HID, wlow, nullptr, GLR,
      BT, GLR, HID, nullptr, nullptr);
  gemm_bt<2, 0><<<dim3(4, 64), blk, 0, stream>>>(wlow, GLR, W_w2, GLR, db, nullptr, KD,
      BT, KD, GLR, b_w2, nullptr);
  // slot 2 -> k  [split MFMA]
  gemm_bt<3, 2><<<dim3(8, 64), blk, 0, stream>>>(xp + 2 * RR, R5, W_x2 + 2 * RR, R5,
      ah, al, HID, BT, HID, RR, x_bias + 2 * HID, x);
  gemm_mfma3<<<dim3(4, 64), blk, 0, stream>>>(ah, al, wkh, wkl, kb, KD, KD, HID);
  // slot 3 -> v  [split MFMA]
  gemm_bt<3, 2><<<dim3(8, 64), blk, 0, stream>>>(xp + 3 * RR, R5, W_x2 + 3 * RR, R5,
      ah, al, HID, BT, HID, RR, x_bias + 3 * HID, x);
  gemm_mfma3<<<dim3(8, 64), blk, 0, stream>>>(ah, al, wvh, wvl, vb, VD, VD, HID);
  // slot 4 -> g  [split MFMA]
  gemm_bt<3, 2><<<dim3(8, 64), blk, 0, stream>>>(xp + 4 * RR, R5, W_x2 + 4 * RR, R5,
      ah, al, HID, BT, HID, RR, x_bias + 4 * HID, x);
  gemm_mfma3<<<dim3(8, 64), blk, 0, stream>>>(ah, al, wgh, wgl, gb, VD, VD, HID);

  // bonus scalar, scan (deep pipeline + DPP), groupnorm+gate, final projection [split MFMA]
  calc_c<<<dim3(BB * NH * TT / 4), blk, 0, stream>>>(rb, kb, bonus, cb);
  scan5_kernel<<<dim3(BB * NH * 32), blk, 0, stream>>>(rb, kb, db, vb, cb, ob);
  gn_gate<<<dim3(BT), blk, 0, stream>>>(ob, gb, gnw, gnb, ah, al);
  gemm_mfma3<<<dim3(8, 64), blk, 0, stream>>>(ah, al, woh, wol, out, HID, HID, HID);
}